// Round 5
// baseline (884.340 us; speedup 1.0000x reference)
//
#include <hip/hip_runtime.h>
#include <hip/hip_bf16.h>
#include <math.h>

// Problem constants
constexpr int kB = 8, kT = 128, kN = 24, kD = 128, kM = 9, kH = 8, kL = 4, kFF = 1024;
constexpr int kF = 16;          // D/H
constexpr int kHD = 16;         // D/H
constexpr int kND = kN * kD;    // 3072
constexpr int kNM = kN * kM;    // 216
constexpr int kP = kB * kT;     // 1024 tokens, p = t*B + b

using bf16x8 = __attribute__((ext_vector_type(8))) short;
using f32x4  = __attribute__((ext_vector_type(4))) float;
typedef __hip_bfloat16 bf16;

__device__ __forceinline__ void load_lds16(const void* g, void* l) {
  __builtin_amdgcn_global_load_lds(
      (const __attribute__((address_space(1))) void*)g,
      (__attribute__((address_space(3))) void*)l, 16, 0, 0);
}

// ---------------------------------------------------------------------------
// MFMA bf16 GEMM, BK=64, XOR-swizzled LDS (conflict-free b128 fragment reads,
// wave-contiguous global_load_lds staging).
// ---------------------------------------------------------------------------
template<int BM, int BN, bool OUTBF>
__global__ __launch_bounds__(256) void mfma_gemm(
    const bf16* __restrict__ A, const bf16* __restrict__ Bm,
    const float* __restrict__ bias, void* __restrict__ Cv,
    int M, int Nc, int K, int ldB, int sAi, int sCi,
    long offAg, long offBg, long offCg, int sBg)
{
  constexpr int WM = BM / 2, WN = BN / 2;
  constexpr int MT = WM / 16, NT = WN / 16;
  constexpr int ASLOTS = BM * 8;   // 16-B slots (BM rows x 128 B per k-chunk)
  constexpr int BSLOTS = BN * 8;
  constexpr int CSTR = BN + 4;     // repack stride (floats)
  __shared__ __align__(16) char smem[(BM + BN) * 64 * 2];
  bf16* As = (bf16*)smem;
  bf16* Bs = (bf16*)(smem + BM * 64 * 2);
  float* Cs = (float*)smem;        // epilogue repack area

  int g = blockIdx.z;
  A  += offAg * g;
  Bm += offBg * g;
  long cbase = offCg * (long)g;
  int bOff = sBg * g;

  int m0 = blockIdx.y * BM, n0 = blockIdx.x * BN;
  int tid = threadIdx.x, lane = tid & 63, wave = tid >> 6;
  int wm = wave >> 1, wn = wave & 1;
  int fr = lane & 15, fq = lane >> 4;

  f32x4 acc[MT][NT] = {};

  for (int kk = 0; kk < K; kk += 64) {
#pragma unroll
    for (int s = tid; s < ASLOTS; s += 256) {
      int m = s >> 3, kq = (s & 7) ^ (m & 7);     // XOR swizzle
      load_lds16(A + (size_t)(m0 + m) * sAi + (kk + kq * 8), &As[s * 8]);
    }
#pragma unroll
    for (int s = tid; s < BSLOTS; s += 256) {
      int n = s >> 3, kq = (s & 7) ^ (n & 7);
      int nr = n0 + n; if (nr > Nc - 1) nr = Nc - 1;   // clamp ragged N
      load_lds16(Bm + (size_t)nr * ldB + (kk + kq * 8), &Bs[s * 8]);
    }
    __syncthreads();
#pragma unroll
    for (int ks = 0; ks < 2; ks++) {
      bf16x8 af[MT], bfr[NT];
#pragma unroll
      for (int i = 0; i < MT; i++) {
        int row = wm * WM + i * 16 + fr;
        af[i] = *(const bf16x8*)&As[row * 64 + (((ks * 4 + fq) ^ (row & 7)) * 8)];
      }
#pragma unroll
      for (int j = 0; j < NT; j++) {
        int row = wn * WN + j * 16 + fr;
        bfr[j] = *(const bf16x8*)&Bs[row * 64 + (((ks * 4 + fq) ^ (row & 7)) * 8)];
      }
#pragma unroll
      for (int i = 0; i < MT; i++)
#pragma unroll
        for (int j = 0; j < NT; j++)
          acc[i][j] = __builtin_amdgcn_mfma_f32_16x16x32_bf16(af[i], bfr[j], acc[i][j], 0, 0, 0);
    }
    __syncthreads();
  }

  // ---- epilogue: per m-tile round, repack 32 rows x BN through LDS ----
  constexpr int NCHUNK = BN / 16;
  int tcol = tid & (NCHUNK - 1);
  int trow = tid / NCHUNK;          // row within the 32-row round
  int colbase = n0 + tcol * 16;
  float vb[16];
  if (trow < 32) {
#pragma unroll
    for (int jj = 0; jj < 16; jj++)
      vb[jj] = bias ? bias[bOff + colbase + jj] : 0.f;
  }
#pragma unroll
  for (int i = 0; i < MT; i++) {
    __syncthreads();
#pragma unroll
    for (int j = 0; j < NT; j++)
#pragma unroll
      for (int r = 0; r < 4; r++)
        Cs[(wm * 16 + fq * 4 + r) * CSTR + wn * WN + j * 16 + fr] = acc[i][j][r];
    __syncthreads();
    if (trow < 32) {
      int row = m0 + (trow >> 4) * WM + i * 16 + (trow & 15);
      float vals[16];
#pragma unroll
      for (int jj = 0; jj < 4; jj++)
        *(float4*)&vals[jj * 4] = *(const float4*)&Cs[trow * CSTR + tcol * 16 + jj * 4];
#pragma unroll
      for (int jj = 0; jj < 16; jj++) vals[jj] += vb[jj];
      if (OUTBF) {
        bf16* cp = (bf16*)Cv + cbase + (size_t)row * sCi + colbase;
        union { bf16 h[8]; uint4 v; } pk;
#pragma unroll
        for (int half = 0; half < 2; half++) {
          if (colbase + half * 8 + 8 <= Nc) {
#pragma unroll
            for (int jj = 0; jj < 8; jj++) pk.h[jj] = __float2bfloat16(vals[half * 8 + jj]);
            *(uint4*)(cp + half * 8) = pk.v;
          }
        }
      } else {
        float* cp = (float*)Cv + cbase + (size_t)row * sCi + colbase;
#pragma unroll
        for (int jj = 0; jj < 4; jj++)
          if (colbase + jj * 4 + 4 <= Nc) *(float4*)(cp + jj * 4) = *(float4*)&vals[jj * 4];
      }
    }
  }
}

// ---------------------------------------------------------------------------
// Mega prep kernel: all weight prep + embedding in ONE dispatch.
// ---------------------------------------------------------------------------
constexpr int NB_EMB = kP;                                     // 1024
constexpr int NB_SPQ = kL * kH * kN;                           // 768
constexpr int NB_SPK = kL * kH * kN;                           // 768
constexpr int NB_SPV = kL * kH * kN;                           // 768
constexpr int NB_TMP = (kL * kN * 384 * kD / 8) / 256;         // 2304
constexpr int NB_CVT = (kL * 24 * 128 * 128 / 8) / 256;        // 768
constexpr int NB_SPB = (kL * 24 * 768) / 256;                  // 288
constexpr int NB_W1  = (kFF / 64) * (kND / 64) * kL;           // 3072
constexpr int NB_W2  = (kND / 64) * (kFF / 64) * kL;           // 3072
constexpr int NB_FIN = ((kNM + 63) / 64) * (kND / 64);         // 192
constexpr int OFF_SPQ = NB_EMB;
constexpr int OFF_SPK = OFF_SPQ + NB_SPQ;
constexpr int OFF_SPV = OFF_SPK + NB_SPK;
constexpr int OFF_TMP = OFF_SPV + NB_SPV;
constexpr int OFF_CVT = OFF_TMP + NB_TMP;
constexpr int OFF_SPB = OFF_CVT + NB_CVT;
constexpr int OFF_W1  = OFF_SPB + NB_SPB;
constexpr int OFF_W2  = OFF_W1 + NB_W1;
constexpr int OFF_FIN = OFF_W2 + NB_W2;
constexpr int NB_PREP = OFF_FIN + NB_FIN;                      // 13024

__device__ __forceinline__ void trans_cvt_body(
    const float* __restrict__ in, bf16* __restrict__ out,
    int R, int C, int bx, int by, float (*t)[65], int tid)
{
  int c0 = bx * 64, r0 = by * 64;
  for (int s = tid; s < 1024; s += 256) {
    int rr = s >> 4, c4 = (s & 15) * 4;
    int r = r0 + rr, c = c0 + c4;
    float4 v;
    if (c + 4 <= C) v = *(const float4*)&in[(size_t)r * C + c];
    else {
      float tmp[4];
#pragma unroll
      for (int j = 0; j < 4; j++) tmp[j] = (c + j < C) ? in[(size_t)r * C + c + j] : 0.f;
      v = *(float4*)tmp;
    }
    *(float4*)&t[rr][c4] = v;
  }
  __syncthreads();
  for (int s = tid; s < 512; s += 256) {
    int cc = s >> 3, r8 = (s & 7) * 8;
    int c = c0 + cc;
    if (c < C) {
      union { bf16 h[8]; uint4 v; } pk;
#pragma unroll
      for (int j = 0; j < 8; j++) pk.h[j] = __float2bfloat16(t[r8 + j][cc]);
      *(uint4*)&out[(size_t)c * R + r0 + r8] = pk.v;
    }
  }
}

// 128x16 fp32 panel (d-major, f innermost) -> 16 rows x 128 bf16 (d innermost).
__device__ __forceinline__ void spw_transpose_body(
    const float* __restrict__ src, bf16* __restrict__ dst, float* ts, int tid)
{
  for (int s = tid; s < 512; s += 256) {
    float4 v = ((const float4*)src)[s];
    int d = s >> 2, f4 = (s & 3) * 4;
    ts[(f4 + 0) * 132 + d] = v.x;
    ts[(f4 + 1) * 132 + d] = v.y;
    ts[(f4 + 2) * 132 + d] = v.z;
    ts[(f4 + 3) * 132 + d] = v.w;
  }
  __syncthreads();
  int f = tid >> 4, d8 = (tid & 15) * 8;
  float4 a = *(const float4*)&ts[f * 132 + d8];
  float4 b = *(const float4*)&ts[f * 132 + d8 + 4];
  union { bf16 h[8]; uint4 v; } pk;
  pk.h[0] = __float2bfloat16(a.x); pk.h[1] = __float2bfloat16(a.y);
  pk.h[2] = __float2bfloat16(a.z); pk.h[3] = __float2bfloat16(a.w);
  pk.h[4] = __float2bfloat16(b.x); pk.h[5] = __float2bfloat16(b.y);
  pk.h[6] = __float2bfloat16(b.z); pk.h[7] = __float2bfloat16(b.w);
  *(uint4*)&dst[(size_t)f * 128 + d8] = pk.v;
}

__global__ __launch_bounds__(256) void prep_kernel(
    const float* __restrict__ sp_Wq, const float* __restrict__ sp_Wk,
    const float* __restrict__ sp_Wv, const float* __restrict__ tmp_Win,
    bf16* __restrict__ spW,
    const float* __restrict__ tmp_Wout, bf16* __restrict__ toWb,
    const float* __restrict__ sp_bq, const float* __restrict__ sp_bk,
    const float* __restrict__ sp_bv, const float* __restrict__ tmp_bin,
    float* __restrict__ spbc,
    const float* __restrict__ ff_W1, bf16* __restrict__ W1t,
    const float* __restrict__ ff_W2, bf16* __restrict__ W2t,
    const float* __restrict__ fin_W, bf16* __restrict__ finWt,
    const float* __restrict__ inp, const float* __restrict__ emb_W,
    const float* __restrict__ emb_b, float* __restrict__ hb,
    bf16* __restrict__ hbb)
{
  __shared__ __align__(16) char sm[64 * 65 * 4];
  int bid = blockIdx.x, tid = threadIdx.x;

  if (bid < OFF_SPQ) {
    // ---- embedding (latency/transcendental-bound: schedule first) ----
    int p = bid;
    int t = p / kB, b = p % kB;
    float* xs = (float*)sm;
    if (tid < kNM)
      xs[tid] = inp[((size_t)b * kT + t) * kNM + tid];
    __syncthreads();
    const float c1 = -logf(10000.f) / (float)kND;
    for (int c4 = tid; c4 < kND / 4; c4 += 256) {
      int c = c4 * 4;
      int n = c >> 7, d = c & 127;
      float4 acc = *(const float4*)&emb_b[n * kD + d];
#pragma unroll
      for (int m = 0; m < kM; m++) {
        float xv = xs[n * kM + m];
        float4 w = *(const float4*)&emb_W[((size_t)(n * kM + m)) * kD + d];
        acc.x += xv * w.x; acc.y += xv * w.y; acc.z += xv * w.z; acc.w += xv * w.w;
      }
      float ang0 = (float)b * expf((float)c * c1);
      float ang1 = (float)b * expf((float)(c + 2) * c1);
      acc.x += sinf(ang0); acc.y += cosf(ang0);
      acc.z += sinf(ang1); acc.w += cosf(ang1);
      *(float4*)&hb[(size_t)p * kND + c] = acc;
      union { bf16 h4[4]; uint2 v; } pk;
      pk.h4[0] = __float2bfloat16(acc.x); pk.h4[1] = __float2bfloat16(acc.y);
      pk.h4[2] = __float2bfloat16(acc.z); pk.h4[3] = __float2bfloat16(acc.w);
      *(uint2*)&hbb[(size_t)p * kND + c] = pk.v;
    }
  } else if (bid < OFF_SPK) {
    // ---- spatial Wq -> spW rows [0,128) ----
    int idx = bid - OFF_SPQ;
    int l = idx / 192, rem = idx % 192;
    int hh = rem / 24, n = rem % 24;
    const float* src = sp_Wq + ((((size_t)l * kH + hh) * kN + n)) * (kD * kF);
    bf16* dst = spW + (((size_t)(l * 24 + n)) * 768 + hh * 16) * 128;
    spw_transpose_body(src, dst, (float*)sm, tid);
  } else if (bid < OFF_SPV) {
    // ---- spatial Wk -> spW rows [128,256) ----
    int idx = bid - OFF_SPK;
    int l = idx / 192, rem = idx % 192;
    int hh = rem / 24, n = rem % 24;
    const float* src = sp_Wk + (((size_t)l * kH + hh)) * (kD * kF);
    bf16* dst = spW + (((size_t)(l * 24 + n)) * 768 + 128 + hh * 16) * 128;
    spw_transpose_body(src, dst, (float*)sm, tid);
  } else if (bid < OFF_TMP) {
    // ---- spatial Wv -> spW rows [256,384) ----
    int idx = bid - OFF_SPV;
    int l = idx / 192, rem = idx % 192;
    int hh = rem / 24, n = rem % 24;
    const float* src = sp_Wv + (((size_t)l * kH + hh)) * (kD * kF);
    bf16* dst = spW + (((size_t)(l * 24 + n)) * 768 + 256 + hh * 16) * 128;
    spw_transpose_body(src, dst, (float*)sm, tid);
  } else if (bid < OFF_CVT) {
    // ---- temporal Win -> spW rows [384,768): contiguous cvt per (l,n) ----
    long j8 = ((long)(bid - OFF_TMP) * 256 + tid) * 8;   // over L*24*49152
    long ln = j8 / 49152, rem = j8 % 49152;
    const float* src = &tmp_Win[ln * 49152 + rem];
    float4 v0 = *(const float4*)src, v1 = *(const float4*)(src + 4);
    union { bf16 h[8]; uint4 v; } pk;
    pk.h[0] = __float2bfloat16(v0.x); pk.h[1] = __float2bfloat16(v0.y);
    pk.h[2] = __float2bfloat16(v0.z); pk.h[3] = __float2bfloat16(v0.w);
    pk.h[4] = __float2bfloat16(v1.x); pk.h[5] = __float2bfloat16(v1.y);
    pk.h[6] = __float2bfloat16(v1.z); pk.h[7] = __float2bfloat16(v1.w);
    *(uint4*)&spW[ln * 98304 + 49152 + rem] = pk.v;
  } else if (bid < OFF_SPB) {
    // ---- cvt toWb ----
    int i8 = ((bid - OFF_CVT) * 256 + tid) * 8;
    float4 v0 = *(const float4*)(tmp_Wout + i8);
    float4 v1 = *(const float4*)(tmp_Wout + i8 + 4);
    union { bf16 h[8]; uint4 v; } pk;
    pk.h[0] = __float2bfloat16(v0.x); pk.h[1] = __float2bfloat16(v0.y);
    pk.h[2] = __float2bfloat16(v0.z); pk.h[3] = __float2bfloat16(v0.w);
    pk.h[4] = __float2bfloat16(v1.x); pk.h[5] = __float2bfloat16(v1.y);
    pk.h[6] = __float2bfloat16(v1.z); pk.h[7] = __float2bfloat16(v1.w);
    *(uint4*)(toWb + i8) = pk.v;
  } else if (bid < OFF_W1) {
    // ---- build_spb ----
    int i = (bid - OFF_SPB) * 256 + tid;
    int r = i % 768;
    int n = (i / 768) % 24;
    int l = i / (768 * 24);
    int hh = (r & 127) >> 4, f = r & 15;
    float v;
    if (r < 128)      v = sp_bq[(((size_t)l * kH + hh) * kN + n) * kF + f];
    else if (r < 256) v = sp_bk[((size_t)l * kH + hh) * kF + f];
    else if (r < 384) v = sp_bv[((size_t)l * kH + hh) * kF + f];
    else              v = tmp_bin[((size_t)l * kN + n) * 384 + (r - 384)];
    spbc[i] = v;
  } else if (bid < OFF_W2) {
    // ---- trans_cvt W1: fp32 (kND x kFF) -> bf16 (kFF x kND), per l ----
    int id2 = bid - OFF_W1;
    int bz = id2 / (16 * 48);
    int rem = id2 % (16 * 48);
    trans_cvt_body(ff_W1 + (size_t)bz * kND * kFF, W1t + (size_t)bz * kFF * kND,
                   kND, kFF, rem % 16, rem / 16, (float(*)[65])sm, tid);
  } else if (bid < OFF_FIN) {
    // ---- trans_cvt W2: fp32 (kFF x kND) -> bf16 (kND x kFF), per l ----
    int id2 = bid - OFF_W2;
    int bz = id2 / (48 * 16);
    int rem = id2 % (48 * 16);
    trans_cvt_body(ff_W2 + (size_t)bz * kFF * kND, W2t + (size_t)bz * kND * kFF,
                   kFF, kND, rem % 48, rem / 48, (float(*)[65])sm, tid);
  } else {
    // ---- trans_cvt fin_W: fp32 (kND x kNM) -> bf16 (kNM x kND) ----
    int id2 = bid - OFF_FIN;
    trans_cvt_body(fin_W, finWt, kND, kNM, id2 % 4, id2 / 4, (float(*)[65])sm, tid);
  }
}

// ---------------------------------------------------------------------------
// Fused attention: blocks [0,kP) spatial, [kP,kP+1536) temporal MFMA.
// Key fix vs r2: temporal Ps ALIASES the dead Qs/Ks region (one extra barrier
// after S=QK^T), so branch-max LDS is 39168 B -> 4 blocks/CU (r2 was 59.9 KB
// -> 2 blocks/CU, which serialized everything).
// ---------------------------------------------------------------------------
__global__ __launch_bounds__(192) void attn_kernel(
    const bf16* __restrict__ qkv, float* __restrict__ sp_out,
    bf16* __restrict__ ot)
{
  __shared__ __align__(16) char smem[39168];
  int tid = threadIdx.x;

  if (blockIdx.x < kP) {
    // ================= spatial attention =================
    int p = blockIdx.x;
    float* s = (float*)smem;                 // 24*388 floats = 37248 B
    for (int i = tid; i < 2304; i += 192) {
      int n = i / 96, c4 = (i % 96) * 4;
      ushort4 u = *(const ushort4*)((const ushort*)qkv + ((size_t)n * kP + p) * 768 + c4);
      float4 f;
      f.x = __bfloat162float(*(const bf16*)&u.x);
      f.y = __bfloat162float(*(const bf16*)&u.y);
      f.z = __bfloat162float(*(const bf16*)&u.z);
      f.w = __bfloat162float(*(const bf16*)&u.w);
      *(float4*)&s[n * 388 + c4] = f;
    }
    __syncthreads();
    int hh = tid / 24, n = tid % 24;
    const float4* qr = (const float4*)(s + n * 388 + hh * 16);
    float4 q0 = qr[0], q1 = qr[1], q2 = qr[2], q3 = qr[3];
    float sc[24];
    float mx = -1e30f;
#pragma unroll
    for (int m = 0; m < 24; m++) {
      const float4* kr = (const float4*)(s + m * 388 + 128 + hh * 16);
      float4 k0 = kr[0], k1 = kr[1], k2 = kr[2], k3 = kr[3];
      float d = q0.x * k0.x + q0.y * k0.y + q0.z * k0.z + q0.w * k0.w
              + q1.x * k1.x + q1.y * k1.y + q1.z * k1.z + q1.w * k1.w
              + q2.x * k2.x + q2.y * k2.y + q2.z * k2.z + q2.w * k2.w
              + q3.x * k3.x + q3.y * k3.y + q3.z * k3.z + q3.w * k3.w;
      d *= 0.25f;
      sc[m] = d;
      mx = fmaxf(mx, d);
    }
    float sum = 0.f;
#pragma unroll
    for (int m = 0; m < 24; m++) { float e = __expf(sc[m] - mx); sc[m] = e; sum += e; }
    float inv = 1.f / sum;
    float4 o0 = {0,0,0,0}, o1 = {0,0,0,0}, o2 = {0,0,0,0}, o3 = {0,0,0,0};
#pragma unroll
    for (int m = 0; m < 24; m++) {
      const float4* vr = (const float4*)(s + m * 388 + 256 + hh * 16);
      float4 v0 = vr[0], v1 = vr[1], v2 = vr[2], v3 = vr[3];
      float w = sc[m];
      o0.x += w * v0.x; o0.y += w * v0.y; o0.z += w * v0.z; o0.w += w * v0.w;
      o1.x += w * v1.x; o1.y += w * v1.y; o1.z += w * v1.z; o1.w += w * v1.w;
      o2.x += w * v2.x; o2.y += w * v2.y; o2.z += w * v2.z; o2.w += w * v2.w;
      o3.x += w * v3.x; o3.y += w * v3.y; o3.z += w * v3.z; o3.w += w * v3.w;
    }
    float* orow = sp_out + (size_t)p * kND + n * kD + hh * 16;
    o0.x *= inv; o0.y *= inv; o0.z *= inv; o0.w *= inv;
    o1.x *= inv; o1.y *= inv; o1.z *= inv; o1.w *= inv;
    o2.x *= inv; o2.y *= inv; o2.z *= inv; o2.w *= inv;
    o3.x *= inv; o3.y *= inv; o3.z *= inv; o3.w *= inv;
    *(float4*)(orow)      = o0;
    *(float4*)(orow + 4)  = o1;
    *(float4*)(orow + 8)  = o2;
    *(float4*)(orow + 12) = o3;
  } else {
    // ================= temporal attention (MFMA) =================
    int g = blockIdx.x - kP;
    int hh = g & 7, n = (g >> 3) % 24, b = g / 192;
    ushort (*Qs)[40]  = (ushort(*)[40])(smem);            // [0,10240)
    ushort (*Ks)[40]  = (ushort(*)[40])(smem + 10240);    // [10240,20480)
    ushort (*Ps)[136] = (ushort(*)[136])(smem);           // [0,34816) aliases Qs/Ks
    ushort (*Vt)[136] = (ushort(*)[136])(smem + 34816);   // [34816,39168)

    for (int idx = tid; idx < 256; idx += 192) {
      int t = idx >> 1, e8 = (idx & 1) * 8;
      const ushort* src = (const ushort*)qkv +
          ((size_t)n * kP + (size_t)t * kB + b) * 768 + 384 + hh * 16 + e8;
      uint4 q = *(const uint4*)(src);
      uint4 k = *(const uint4*)(src + 128);
      uint4 v = *(const uint4*)(src + 256);
      *(uint4*)&Qs[t][e8] = q;
      *(uint4*)&Ks[t][e8] = k;
      *(uint4*)&Qs[t][16 + e8] = make_uint4(0, 0, 0, 0);
      *(uint4*)&Ks[t][16 + e8] = make_uint4(0, 0, 0, 0);
      const ushort* vp = (const ushort*)&v;
#pragma unroll
      for (int j = 0; j < 8; j++) Vt[e8 + j][t] = vp[j];
    }
    __syncthreads();

    int lane = tid & 63, w = tid >> 6;
    int c = lane & 15, quad = lane >> 4;

    // S = Q K^T (Qs/Ks consumed entirely into registers here)
    f32x4 acc[4][8];
    if (w < 2) {
      bf16x8 aq[4];
#pragma unroll
      for (int mt = 0; mt < 4; mt++)
        aq[mt] = *(const bf16x8*)&Qs[w * 64 + mt * 16 + c][quad * 8];
#pragma unroll
      for (int nt = 0; nt < 8; nt++) {
        bf16x8 bk = *(const bf16x8*)&Ks[nt * 16 + c][quad * 8];
#pragma unroll
        for (int mt = 0; mt < 4; mt++) {
          f32x4 z = {0.f, 0.f, 0.f, 0.f};
          acc[mt][nt] = __builtin_amdgcn_mfma_f32_16x16x32_bf16(aq[mt], bk, z, 0, 0, 0);
        }
      }
    }
    __syncthreads();   // Qs/Ks dead across the whole block -> Ps may overwrite

    if (w < 2) {
      // softmax per row; rows t = w*64 + mt*16 + quad*4 + r, cols s = nt*16 + c
      f32x4 invv[4];
#pragma unroll
      for (int mt = 0; mt < 4; mt++) {
        int tbase = w * 64 + mt * 16 + quad * 4;
        f32x4 rm = {-1e30f, -1e30f, -1e30f, -1e30f};
#pragma unroll
        for (int nt = 0; nt < 8; nt++) {
          int s = nt * 16 + c;
#pragma unroll
          for (int r = 0; r < 4; r++) {
            float x = acc[mt][nt][r] * 0.25f + ((s < tbase + r) ? 1.f : 0.f);
            acc[mt][nt][r] = x;
            rm[r] = fmaxf(rm[r], x);
          }
        }
#pragma unroll
        for (int off = 1; off < 16; off <<= 1)
#pragma unroll
          for (int r = 0; r < 4; r++) rm[r] = fmaxf(rm[r], __shfl_xor(rm[r], off, 64));
        f32x4 rs = {0.f, 0.f, 0.f, 0.f};
#pragma unroll
        for (int nt = 0; nt < 8; nt++)
#pragma unroll
          for (int r = 0; r < 4; r++) {
            float pp = __expf(acc[mt][nt][r] - rm[r]);
            acc[mt][nt][r] = pp;
            rs[r] += pp;
          }
#pragma unroll
        for (int off = 1; off < 16; off <<= 1)
#pragma unroll
          for (int r = 0; r < 4; r++) rs[r] += __shfl_xor(rs[r], off, 64);
#pragma unroll
        for (int r = 0; r < 4; r++) invv[mt][r] = 1.f / rs[r];
#pragma unroll
        for (int nt = 0; nt < 8; nt++)
#pragma unroll
          for (int r = 0; r < 4; r++) {
            bf16 pb = __float2bfloat16(acc[mt][nt][r]);
            Ps[tbase + r][nt * 16 + c] = *(ushort*)&pb;
          }
      }

      // O = P V (in-wave Ps reuse only)
      f32x4 o[4] = {};
#pragma unroll
      for (int ks = 0; ks < 128; ks += 32) {
        bf16x8 bv = *(const bf16x8*)&Vt[c][ks + quad * 8];
#pragma unroll
        for (int mt = 0; mt < 4; mt++) {
          bf16x8 ap = *(const bf16x8*)&Ps[w * 64 + mt * 16 + c][ks + quad * 8];
          o[mt] = __builtin_amdgcn_mfma_f32_16x16x32_bf16(ap, bv, o[mt], 0, 0, 0);
        }
      }

#pragma unroll
      for (int mt = 0; mt < 4; mt++) {
#pragma unroll
        for (int r = 0; r < 4; r++) {
          int t = w * 64 + mt * 16 + quad * 4 + r;
          float val = o[mt][r] * invv[mt][r];
          ot[((size_t)n * kP + (size_t)t * kB + b) * 128 + hh * 16 + c] = __float2bfloat16(val);
        }
      }
    }
  }
}

// ---------------------------------------------------------------------------
// Fused: a2 = LN(sp+h) + LN(tp+h); float4 traffic; writes a2 fp32 + bf16
// ---------------------------------------------------------------------------
__global__ __launch_bounds__(256) void fuse_a2_kernel(
    const float* __restrict__ sp, const float* __restrict__ tp,
    const float* __restrict__ h, const float* __restrict__ g,
    const float* __restrict__ be, float* __restrict__ a2, bf16* __restrict__ a2b)
{
  int row = blockIdx.x;
  const float4* s1p = (const float4*)(sp + (size_t)row * kND);
  const float4* s2p = (const float4*)(tp + (size_t)row * kND);
  const float4* hp  = (const float4*)(h  + (size_t)row * kND);
  float4 x1[3], x2[3];
  float sum1 = 0.f, sum2 = 0.f;
#pragma unroll
  for (int i = 0; i < 3; i++) {
    int c = threadIdx.x + 256 * i;
    float4 hv = hp[c], a = s1p[c], bb = s2p[c];
    a.x += hv.x; a.y += hv.y; a.z += hv.z; a.w += hv.w;
    bb.x += hv.x; bb.y += hv.y; bb.z += hv.z; bb.w += hv.w;
    x1[i] = a; x2[i] = bb;
    sum1 += a.x + a.y + a.z + a.w;
    sum2 += bb.x + bb.y + bb.z + bb.w;
  }
  __shared__ float red1[4], red2[4];
#pragma unroll
  for (int o = 32; o > 0; o >>= 1) { sum1 += __shfl_down(sum1, o, 64); sum2 += __shfl_down(sum2, o, 64); }
  int wid = threadIdx.x >> 6;
  if ((threadIdx.x & 63) == 0) { red1[wid] = sum1; red2[wid] = sum2; }
  __syncthreads();
  float mean1 = (red1[0] + red1[1] + red1[2] + red1[3]) * (1.f / kND);
  float mean2 = (red2[0] + red2[1] + red2[2] + red2[3]) * (1.f / kND);
  __syncthreads();
  float v1 = 0.f, v2 = 0.f;
#pragma unroll
  for (int i = 0; i < 3; i++) {
    float4 a = x1[i], bb = x2[i];
    v1 += (a.x - mean1) * (a.x - mean1) + (a.y - mean1) * (a.y - mean1)
        + (a.z - mean1) * (a.z - mean1) + (a.w - mean1) * (a.w - mean1);
    v2 += (bb.x - mean2) * (bb.x - mean2) + (bb.y - mean2) * (bb.y - mean2)
        + (bb.z - mean2) * (bb.z - mean2) + (bb.w - mean2) * (bb.w - mean2);
  }
#pragma unroll
  for (int o = 32; o > 0; o >>= 1) { v1 += __shfl_down(v1, o, 64); v2 += __shfl_down(v2, o, 64); }
  if ((threadIdx.x & 63) == 0) { red1[wid] = v1; red2[wid] = v2; }
  __syncthreads();
  float r1 = rsqrtf((red1[0] + red1[1] + red1[2] + red1[3]) * (1.f / kND) + 1e-5f);
  float r2 = rsqrtf((red2[0] + red2[1] + red2[2] + red2[3]) * (1.f / kND) + 1e-5f);
  const float4* g4 = (const float4*)g;
  const float4* b4 = (const float4*)be;
#pragma unroll
  for (int i = 0; i < 3; i++) {
    int c = threadIdx.x + 256 * i;
    float4 gc = g4[c], bc = b4[c];
    float4 a = x1[i], bb = x2[i], o;
    o.x = (a.x - mean1) * r1 * gc.x + bc.x + (bb.x - mean2) * r2 * gc.x + bc.x;
    o.y = (a.y - mean1) * r1 * gc.y + bc.y + (bb.y - mean2) * r2 * gc.y + bc.y;
    o.z = (a.z - mean1) * r1 * gc.z + bc.z + (bb.z - mean2) * r2 * gc.z + bc.z;
    o.w = (a.w - mean1) * r1 * gc.w + bc.w + (bb.w - mean2) * r2 * gc.w + bc.w;
    *(float4*)(a2 + (size_t)row * kND + c * 4) = o;
    union { bf16 h4[4]; uint2 v; } pk;
    pk.h4[0] = __float2bfloat16(o.x); pk.h4[1] = __float2bfloat16(o.y);
    pk.h4[2] = __float2bfloat16(o.z); pk.h4[3] = __float2bfloat16(o.w);
    *(uint2*)(a2b + (size_t)row * kND + c * 4) = pk.v;
  }
}

// out = LN(a + b); float4 traffic; writes fp32 + bf16
__global__ __launch_bounds__(256) void add_ln_dual_kernel(
    const float* __restrict__ a, const float* __restrict__ b,
    const float* __restrict__ g, const float* __restrict__ be,
    float* __restrict__ out, bf16* __restrict__ outb)
{
  int row = blockIdx.x;
  const float4* ar = (const float4*)(a + (size_t)row * kND);
  const float4* br = (const float4*)(b + (size_t)row * kND);
  float4 v[3];
  float s = 0.f;
#pragma unroll
  for (int i = 0; i < 3; i++) {
    int c = threadIdx.x + 256 * i;
    float4 x = ar[c], y = br[c];
    x.x += y.x; x.y += y.y; x.z += y.z; x.w += y.w;
    v[i] = x;
    s += x.x + x.y + x.z + x.w;
  }
  __shared__ float red[4];
#pragma unroll
  for (int o = 32; o > 0; o >>= 1) s += __shfl_down(s, o, 64);
  int wid = threadIdx.x >> 6;
  if ((threadIdx.x & 63) == 0) red[wid] = s;
  __syncthreads();
  float mean = (red[0] + red[1] + red[2] + red[3]) * (1.f / kND);
  __syncthreads();
  float vs = 0.f;
#pragma unroll
  for (int i = 0; i < 3; i++) {
    float4 x = v[i];
    vs += (x.x - mean) * (x.x - mean) + (x.y - mean) * (x.y - mean)
        + (x.z - mean) * (x.z - mean) + (x.w - mean) * (x.w - mean);
  }
#pragma unroll
  for (int o = 32; o > 0; o >>= 1) vs += __shfl_down(vs, o, 64);
  if ((threadIdx.x & 63) == 0) red[wid] = vs;
  __syncthreads();
  float rstd = rsqrtf((red[0] + red[1] + red[2] + red[3]) * (1.f / kND) + 1e-5f);
  const float4* g4 = (const float4*)g;
  const float4* b4 = (const float4*)be;
#pragma unroll
  for (int i = 0; i < 3; i++) {
    int c = threadIdx.x + 256 * i;
    float4 gc = g4[c], bc = b4[c], x = v[i], o;
    o.x = (x.x - mean) * rstd * gc.x + bc.x;
    o.y = (x.y - mean) * rstd * gc.y + bc.y;
    o.z = (x.z - mean) * rstd * gc.z + bc.z;
    o.w = (x.w - mean) * rstd * gc.w + bc.w;
    *(float4*)(out + (size_t)row * kND + c * 4) = o;
    union { bf16 h4[4]; uint2 v2; } pk;
    pk.h4[0] = __float2bfloat16(o.x); pk.h4[1] = __float2bfloat16(o.y);
    pk.h4[2] = __float2bfloat16(o.z); pk.h4[3] = __float2bfloat16(o.w);
    *(uint2*)(outb + (size_t)row * kND + c * 4) = pk.v2;
  }
}

// FF1 split-K reduce: f1b[i] = bf16(p0+p1+p2 + bias[col])
__global__ __launch_bounds__(256) void ff1_reduce_kernel(
    const float* __restrict__ part, const float* __restrict__ bias,
    bf16* __restrict__ out)
{
  int i4 = (blockIdx.x * 256 + threadIdx.x) * 4;   // grid covers kP*kFF/4
  const size_t S = (size_t)kP * kFF;
  float4 p0 = *(const float4*)(part + i4);
  float4 p1 = *(const float4*)(part + S + i4);
  float4 p2 = *(const float4*)(part + 2 * S + i4);
  int col = i4 & (kFF - 1);
  float4 bb = *(const float4*)(bias + col);
  union { bf16 h4[4]; uint2 v; } pk;
  pk.h4[0] = __float2bfloat16(p0.x + p1.x + p2.x + bb.x);
  pk.h4[1] = __float2bfloat16(p0.y + p1.y + p2.y + bb.y);
  pk.h4[2] = __float2bfloat16(p0.z + p1.z + p2.z + bb.z);
  pk.h4[3] = __float2bfloat16(p0.w + p1.w + p2.w + bb.w);
  *(uint2*)(out + i4) = pk.v;
}

// Final: out[b,t,c] = sum_z part[z][(t*B+b)*216+c] + fin_b[c] + inputs[b,t,c]
__global__ __launch_bounds__(256) void final_reduce_add_kernel(
    const float* __restrict__ part, const float* __restrict__ fin_b,
    const float* __restrict__ inp, float* __restrict__ out)
{
  int i = blockIdx.x * 256 + threadIdx.x;
  if (i >= kB * kT * kNM) return;
  int c = i % kNM;
  int rem = i / kNM;
  int t = rem % kT, b = rem / kT;
  size_t pi = (size_t)(t * kB + b) * kNM + c;
  const size_t S = (size_t)kP * kNM;
  float v = fin_b[c] + inp[i];
#pragma unroll
  for (int z = 0; z < 8; z++) v += part[z * S + pi];
  out[i] = v;
}

// ---------------------------------------------------------------------------
extern "C" void kernel_launch(void* const* d_in, const int* in_sizes, int n_in,
                              void* d_out, int out_size, void* d_ws, size_t ws_size,
                              hipStream_t stream)
{
  const float* inputs   = (const float*)d_in[0];
  const float* emb_W    = (const float*)d_in[1];
  const float* emb_b    = (const float*)d_in[2];
  const float* sp_Wq    = (const float*)d_in[3];
  const float* sp_bq    = (const float*)d_in[4];
  const float* sp_Wk    = (const float*)d_in[5];
  const float* sp_bk    = (const float*)d_in[6];
  const float* sp_Wv    = (const float*)d_in[7];
  const float* sp_bv    = (const float*)d_in[8];
  const float* tmp_Win  = (const float*)d_in[9];
  const float* tmp_bin  = (const float*)d_in[10];
  const float* tmp_Wout = (const float*)d_in[11];
  const float* tmp_bout = (const float*)d_in[12];
  const float* ff_W1    = (const float*)d_in[13];
  const float* ff_b1    = (const float*)d_in[14];
  const float* ff_W2    = (const float*)d_in[15];
  const float* ff_b2    = (const float*)d_in[16];
  const float* ln_g     = (const float*)d_in[17];
  const float* ln_b     = (const float*)d_in[18];
  const float* fin_W    = (const float*)d_in[19];
  const float* fin_b    = (const float*)d_in[20];
  float* out = (float*)d_out;

  // ---- workspace layout ----
  char* wp = (char*)d_ws;
  size_t off = 0;
  auto alloc = [&](size_t bytes) { void* p = wp + off; off += (bytes + 255) & ~(size_t)255; return p; };
  bf16* spW   = (bf16*)alloc((size_t)kL * 24 * 768 * 128 * 2);  // fused qkv weights
  bf16* toWb  = (bf16*)alloc((size_t)kL * 24 * 128 * 128 * 2);
  bf16* W1t   = (bf16*)alloc((size_t)kL * kFF * kND * 2);
  bf16* W2t   = (bf16*)alloc((size_t)kL * kND * kFF * 2);
  bf16* finWt = (bf16*)alloc((size_t)kNM * kND * 2);
  float* spbc = (float*)alloc((size_t)kL * 24 * 768 * 4);
  float* hb   = (float*)alloc((size_t)kP * kND * 4);
  bf16*  hbb  = (bf16*) alloc((size_t)kP * kND * 2);
  bf16*  qkvb = (bf16*) alloc((size_t)24 * kP * 768 * 2);   // fused spatial+temporal qkv
  float* sp   = (float*)alloc((size_t)kP * kND * 4);        // spatial out; FF1 partials
  float* tp   = (float*)alloc((size_t)kP * kND * 4);        // temporal out; FF2 out; final partials
  float* a2   = (float*)alloc((size_t)kP * kND * 4);
  bf16*  a2b  = (bf16*) alloc((size_t)kP * kND * 2);
  bf16*  f1b  = (bf16*) alloc((size_t)kP * kFF * 2);
  bf16*  otb  = (bf16*) alloc((size_t)24 * kP * 128 * 2);
  float* ffpart  = sp;   // 3 * kP*kFF fp32 = 12 MB (sp dead during FF)
  float* finpart = tp;   // 8 * kP*kNM fp32 = 6.9 MB (tp dead after loop)

  // ---- all weight prep + embedding: ONE dispatch ----
  prep_kernel<<<NB_PREP, 256, 0, stream>>>(
      sp_Wq, sp_Wk, sp_Wv, tmp_Win, spW,
      tmp_Wout, toWb,
      sp_bq, sp_bk, sp_bv, tmp_bin, spbc,
      ff_W1, W1t, ff_W2, W2t, fin_W, finWt,
      inputs, emb_W, emb_b, hb, hbb);

  for (int l = 0; l < kL; l++) {
    const float* lg = ln_g + (size_t)l * kND;
    const float* lb = ln_b + (size_t)l * kND;

    // fused spatial+temporal qkv: groups n; C = qkvb (n, p, 768) bf16
    mfma_gemm<128, 128, true><<<dim3(6, 8, 24), 256, 0, stream>>>(
        hbb, spW + (size_t)l * 24 * 768 * 128, spbc + (size_t)l * 24 * 768, qkvb,
        kP, 768, 128, /*ldB*/128, /*sAi*/kND, /*sCi*/768,
        /*offAg*/128, /*offBg*/768 * 128, /*offCg*/(long)kP * 768, /*sBg*/768);

    // spatial + temporal attention, one dispatch (LDS-balanced branches)
    attn_kernel<<<kP + kB * 24 * 8, 192, 0, stream>>>(qkvb, sp, otb);

    // temporal out-proj: 64x64 tiles -> 768 blocks (3 blocks/CU)
    mfma_gemm<64, 64, false><<<dim3(2, 16, 24), 256, 0, stream>>>(
        otb, toWb + (size_t)l * 24 * 128 * 128, tmp_bout + (size_t)l * 24 * 128, tp,
        kP, 128, 128, /*ldB*/128, /*sAi*/128, /*sCi*/kND,
        /*offAg*/(long)kP * 128, /*offBg*/128 * 128, /*offCg*/128, /*sBg*/128);

    fuse_a2_kernel<<<kP, 256, 0, stream>>>(sp, tp, hb, lg, lb, a2, a2b);

    // FF1 split-K=3: 768 blocks, K-chunk 1024, fp32 partials -> ffpart
    mfma_gemm<64, 64, false><<<dim3(kFF / 64, kP / 64, 3), 256, 0, stream>>>(
        a2b, W1t + (size_t)l * kFF * kND, nullptr, ffpart,
        kP, kFF, /*K*/kND / 3, /*ldB*/kND, /*sAi*/kND, /*sCi*/kFF,
        /*offAg*/kND / 3, /*offBg*/kND / 3, /*offCg*/(long)kP * kFF, /*sBg*/0);
    ff1_reduce_kernel<<<(kP * kFF / 4) / 256, 256, 0, stream>>>(
        ffpart, ff_b1 + (size_t)l * kFF, f1b);

    // FF2: 64x64 tiles -> 768 blocks
    mfma_gemm<64, 64, false><<<dim3(kND / 64, kP / 64, 1), 256, 0, stream>>>(
        f1b, W2t + (size_t)l * kND * kFF, ff_b2 + (size_t)l * kND, tp,
        kP, kND, kFF, /*ldB*/kFF, /*sAi*/kFF, /*sCi*/kND, 0, 0, 0, 0);

    add_ln_dual_kernel<<<kP, 256, 0, stream>>>(tp, a2, lg, lb, hb, hbb);
  }

  // final projection: split-K=8 (K-chunk 384) -> 512 blocks; fused reduce+residual
  mfma_gemm<64, 64, false><<<dim3((kNM + 63) / 64, kP / 64, 8), 256, 0, stream>>>(
      hbb, finWt, nullptr, finpart,
      kP, kNM, /*K*/kND / 8, /*ldB*/kND, /*sAi*/kND, /*sCi*/kNM,
      /*offAg*/kND / 8, /*offBg*/kND / 8, /*offCg*/(long)kP * kNM, /*sBg*/0);
  final_reduce_add_kernel<<<(kB * kT * kNM + 255) / 256, 256, 0, stream>>>(
      finpart, fin_b, inputs, out);
}

// Round 6
// 844.065 us; speedup vs baseline: 1.0477x; 1.0477x over previous
//
#include <hip/hip_runtime.h>
#include <hip/hip_bf16.h>
#include <math.h>

// Problem constants
constexpr int kB = 8, kT = 128, kN = 24, kD = 128, kM = 9, kH = 8, kL = 4, kFF = 1024;
constexpr int kF = 16;          // D/H
constexpr int kHD = 16;         // D/H
constexpr int kND = kN * kD;    // 3072
constexpr int kNM = kN * kM;    // 216
constexpr int kP = kB * kT;     // 1024 tokens, p = t*B + b

using bf16x8 = __attribute__((ext_vector_type(8))) short;
using f32x4  = __attribute__((ext_vector_type(4))) float;
typedef __hip_bfloat16 bf16;

__device__ __forceinline__ void load_lds16(const void* g, void* l) {
  __builtin_amdgcn_global_load_lds(
      (const __attribute__((address_space(1))) void*)g,
      (__attribute__((address_space(3))) void*)l, 16, 0, 0);
}

// ---------------------------------------------------------------------------
// MFMA bf16 GEMM, BK=64, XOR-swizzled LDS.
// AMODE 0: A staged via global_load_lds from bf16 A.
// AMODE 1: A staged via registers = ffpart[0]+ffpart[1]+ffpart[2]+aBias (fp32),
//          cvt to bf16 (identical arithmetic to the old ff1_reduce kernel).
// ---------------------------------------------------------------------------
template<int BM, int BN, bool OUTBF, int AMODE = 0>
__global__ __launch_bounds__(256) void mfma_gemm(
    const bf16* __restrict__ A, const bf16* __restrict__ Bm,
    const float* __restrict__ bias, void* __restrict__ Cv,
    int M, int Nc, int K, int ldB, int sAi, int sCi,
    long offAg, long offBg, long offCg, int sBg,
    const float* __restrict__ aSrcF = nullptr,
    const float* __restrict__ aBias = nullptr)
{
  constexpr int WM = BM / 2, WN = BN / 2;
  constexpr int MT = WM / 16, NT = WN / 16;
  constexpr int ASLOTS = BM * 8;   // 16-B slots (BM rows x 128 B per k-chunk)
  constexpr int BSLOTS = BN * 8;
  constexpr int CSTR = BN + 4;     // repack stride (floats)
  __shared__ __align__(16) char smem[(BM + BN) * 64 * 2];
  bf16* As = (bf16*)smem;
  bf16* Bs = (bf16*)(smem + BM * 64 * 2);
  float* Cs = (float*)smem;        // epilogue repack area

  int g = blockIdx.z;
  A  += offAg * g;
  Bm += offBg * g;
  long cbase = offCg * (long)g;
  int bOff = sBg * g;

  int m0 = blockIdx.y * BM, n0 = blockIdx.x * BN;
  int tid = threadIdx.x, lane = tid & 63, wave = tid >> 6;
  int wm = wave >> 1, wn = wave & 1;
  int fr = lane & 15, fq = lane >> 4;

  f32x4 acc[MT][NT] = {};

  for (int kk = 0; kk < K; kk += 64) {
    if constexpr (AMODE == 1) {
      const size_t SR = (size_t)kP * kFF;
#pragma unroll
      for (int s = tid; s < ASLOTS; s += 256) {
        int m = s >> 3, kq = (s & 7) ^ (m & 7);     // XOR swizzle
        const float* p = aSrcF + (size_t)(m0 + m) * kFF + (kk + kq * 8);
        union { bf16 h[8]; bf16x8 v; } pk;
#pragma unroll
        for (int j = 0; j < 8; j += 4) {
          float4 p0 = *(const float4*)(p + j);
          float4 p1 = *(const float4*)(p + SR + j);
          float4 p2 = *(const float4*)(p + 2 * SR + j);
          float4 bb = *(const float4*)(aBias + kk + kq * 8 + j);
          pk.h[j + 0] = __float2bfloat16(p0.x + p1.x + p2.x + bb.x);
          pk.h[j + 1] = __float2bfloat16(p0.y + p1.y + p2.y + bb.y);
          pk.h[j + 2] = __float2bfloat16(p0.z + p1.z + p2.z + bb.z);
          pk.h[j + 3] = __float2bfloat16(p0.w + p1.w + p2.w + bb.w);
        }
        *(bf16x8*)&As[s * 8] = pk.v;
      }
    } else {
#pragma unroll
      for (int s = tid; s < ASLOTS; s += 256) {
        int m = s >> 3, kq = (s & 7) ^ (m & 7);     // XOR swizzle
        load_lds16(A + (size_t)(m0 + m) * sAi + (kk + kq * 8), &As[s * 8]);
      }
    }
#pragma unroll
    for (int s = tid; s < BSLOTS; s += 256) {
      int n = s >> 3, kq = (s & 7) ^ (n & 7);
      int nr = n0 + n; if (nr > Nc - 1) nr = Nc - 1;   // clamp ragged N
      load_lds16(Bm + (size_t)nr * ldB + (kk + kq * 8), &Bs[s * 8]);
    }
    __syncthreads();
#pragma unroll
    for (int ks = 0; ks < 2; ks++) {
      bf16x8 af[MT], bfr[NT];
#pragma unroll
      for (int i = 0; i < MT; i++) {
        int row = wm * WM + i * 16 + fr;
        af[i] = *(const bf16x8*)&As[row * 64 + (((ks * 4 + fq) ^ (row & 7)) * 8)];
      }
#pragma unroll
      for (int j = 0; j < NT; j++) {
        int row = wn * WN + j * 16 + fr;
        bfr[j] = *(const bf16x8*)&Bs[row * 64 + (((ks * 4 + fq) ^ (row & 7)) * 8)];
      }
#pragma unroll
      for (int i = 0; i < MT; i++)
#pragma unroll
        for (int j = 0; j < NT; j++)
          acc[i][j] = __builtin_amdgcn_mfma_f32_16x16x32_bf16(af[i], bfr[j], acc[i][j], 0, 0, 0);
    }
    __syncthreads();
  }

  // ---- epilogue: per m-tile round, repack 32 rows x BN through LDS ----
  constexpr int NCHUNK = BN / 16;
  int tcol = tid & (NCHUNK - 1);
  int trow = tid / NCHUNK;          // row within the 32-row round
  int colbase = n0 + tcol * 16;
  float vb[16];
  if (trow < 32) {
#pragma unroll
    for (int jj = 0; jj < 16; jj++)
      vb[jj] = bias ? bias[bOff + colbase + jj] : 0.f;
  }
#pragma unroll
  for (int i = 0; i < MT; i++) {
    __syncthreads();
#pragma unroll
    for (int j = 0; j < NT; j++)
#pragma unroll
      for (int r = 0; r < 4; r++)
        Cs[(wm * 16 + fq * 4 + r) * CSTR + wn * WN + j * 16 + fr] = acc[i][j][r];
    __syncthreads();
    if (trow < 32) {
      int row = m0 + (trow >> 4) * WM + i * 16 + (trow & 15);
      float vals[16];
#pragma unroll
      for (int jj = 0; jj < 4; jj++)
        *(float4*)&vals[jj * 4] = *(const float4*)&Cs[trow * CSTR + tcol * 16 + jj * 4];
#pragma unroll
      for (int jj = 0; jj < 16; jj++) vals[jj] += vb[jj];
      if (OUTBF) {
        bf16* cp = (bf16*)Cv + cbase + (size_t)row * sCi + colbase;
        union { bf16 h[8]; uint4 v; } pk;
#pragma unroll
        for (int half = 0; half < 2; half++) {
          if (colbase + half * 8 + 8 <= Nc) {
#pragma unroll
            for (int jj = 0; jj < 8; jj++) pk.h[jj] = __float2bfloat16(vals[half * 8 + jj]);
            *(uint4*)(cp + half * 8) = pk.v;
          }
        }
      } else {
        float* cp = (float*)Cv + cbase + (size_t)row * sCi + colbase;
#pragma unroll
        for (int jj = 0; jj < 4; jj++)
          if (colbase + jj * 4 + 4 <= Nc) *(float4*)(cp + jj * 4) = *(float4*)&vals[jj * 4];
      }
    }
  }
}

// ---------------------------------------------------------------------------
// Mega prep kernel: all weight prep + embedding in ONE dispatch.
// ---------------------------------------------------------------------------
constexpr int NB_EMB = kP;                                     // 1024
constexpr int NB_SPQ = kL * kH * kN;                           // 768
constexpr int NB_SPK = kL * kH * kN;                           // 768
constexpr int NB_SPV = kL * kH * kN;                           // 768
constexpr int NB_TMP = (kL * kN * 384 * kD / 8) / 256;         // 2304
constexpr int NB_CVT = (kL * 24 * 128 * 128 / 8) / 256;        // 768
constexpr int NB_SPB = (kL * 24 * 768) / 256;                  // 288
constexpr int NB_W1  = (kFF / 64) * (kND / 64) * kL;           // 3072
constexpr int NB_W2  = (kND / 64) * (kFF / 64) * kL;           // 3072
constexpr int NB_FIN = ((kNM + 63) / 64) * (kND / 64);         // 192
constexpr int OFF_SPQ = NB_EMB;
constexpr int OFF_SPK = OFF_SPQ + NB_SPQ;
constexpr int OFF_SPV = OFF_SPK + NB_SPK;
constexpr int OFF_TMP = OFF_SPV + NB_SPV;
constexpr int OFF_CVT = OFF_TMP + NB_TMP;
constexpr int OFF_SPB = OFF_CVT + NB_CVT;
constexpr int OFF_W1  = OFF_SPB + NB_SPB;
constexpr int OFF_W2  = OFF_W1 + NB_W1;
constexpr int OFF_FIN = OFF_W2 + NB_W2;
constexpr int NB_PREP = OFF_FIN + NB_FIN;                      // 13024

__device__ __forceinline__ void trans_cvt_body(
    const float* __restrict__ in, bf16* __restrict__ out,
    int R, int C, int bx, int by, float (*t)[65], int tid)
{
  int c0 = bx * 64, r0 = by * 64;
  for (int s = tid; s < 1024; s += 256) {
    int rr = s >> 4, c4 = (s & 15) * 4;
    int r = r0 + rr, c = c0 + c4;
    float4 v;
    if (c + 4 <= C) v = *(const float4*)&in[(size_t)r * C + c];
    else {
      float tmp[4];
#pragma unroll
      for (int j = 0; j < 4; j++) tmp[j] = (c + j < C) ? in[(size_t)r * C + c + j] : 0.f;
      v = *(float4*)tmp;
    }
    *(float4*)&t[rr][c4] = v;
  }
  __syncthreads();
  for (int s = tid; s < 512; s += 256) {
    int cc = s >> 3, r8 = (s & 7) * 8;
    int c = c0 + cc;
    if (c < C) {
      union { bf16 h[8]; uint4 v; } pk;
#pragma unroll
      for (int j = 0; j < 8; j++) pk.h[j] = __float2bfloat16(t[r8 + j][cc]);
      *(uint4*)&out[(size_t)c * R + r0 + r8] = pk.v;
    }
  }
}

// 128x16 fp32 panel (d-major, f innermost) -> 16 rows x 128 bf16 (d innermost).
__device__ __forceinline__ void spw_transpose_body(
    const float* __restrict__ src, bf16* __restrict__ dst, float* ts, int tid)
{
  for (int s = tid; s < 512; s += 256) {
    float4 v = ((const float4*)src)[s];
    int d = s >> 2, f4 = (s & 3) * 4;
    ts[(f4 + 0) * 132 + d] = v.x;
    ts[(f4 + 1) * 132 + d] = v.y;
    ts[(f4 + 2) * 132 + d] = v.z;
    ts[(f4 + 3) * 132 + d] = v.w;
  }
  __syncthreads();
  int f = tid >> 4, d8 = (tid & 15) * 8;
  float4 a = *(const float4*)&ts[f * 132 + d8];
  float4 b = *(const float4*)&ts[f * 132 + d8 + 4];
  union { bf16 h[8]; uint4 v; } pk;
  pk.h[0] = __float2bfloat16(a.x); pk.h[1] = __float2bfloat16(a.y);
  pk.h[2] = __float2bfloat16(a.z); pk.h[3] = __float2bfloat16(a.w);
  pk.h[4] = __float2bfloat16(b.x); pk.h[5] = __float2bfloat16(b.y);
  pk.h[6] = __float2bfloat16(b.z); pk.h[7] = __float2bfloat16(b.w);
  *(uint4*)&dst[(size_t)f * 128 + d8] = pk.v;
}

__global__ __launch_bounds__(256) void prep_kernel(
    const float* __restrict__ sp_Wq, const float* __restrict__ sp_Wk,
    const float* __restrict__ sp_Wv, const float* __restrict__ tmp_Win,
    bf16* __restrict__ spW,
    const float* __restrict__ tmp_Wout, bf16* __restrict__ toWb,
    const float* __restrict__ sp_bq, const float* __restrict__ sp_bk,
    const float* __restrict__ sp_bv, const float* __restrict__ tmp_bin,
    float* __restrict__ spbc,
    const float* __restrict__ ff_W1, bf16* __restrict__ W1t,
    const float* __restrict__ ff_W2, bf16* __restrict__ W2t,
    const float* __restrict__ fin_W, bf16* __restrict__ finWt,
    const float* __restrict__ inp, const float* __restrict__ emb_W,
    const float* __restrict__ emb_b, float* __restrict__ hb,
    bf16* __restrict__ hbb)
{
  __shared__ __align__(16) char sm[64 * 65 * 4];
  int bid = blockIdx.x, tid = threadIdx.x;

  if (bid < OFF_SPQ) {
    // ---- embedding (latency/transcendental-bound: schedule first) ----
    int p = bid;
    int t = p / kB, b = p % kB;
    float* xs = (float*)sm;
    if (tid < kNM)
      xs[tid] = inp[((size_t)b * kT + t) * kNM + tid];
    __syncthreads();
    const float c1 = -logf(10000.f) / (float)kND;
    for (int c4 = tid; c4 < kND / 4; c4 += 256) {
      int c = c4 * 4;
      int n = c >> 7, d = c & 127;
      float4 acc = *(const float4*)&emb_b[n * kD + d];
#pragma unroll
      for (int m = 0; m < kM; m++) {
        float xv = xs[n * kM + m];
        float4 w = *(const float4*)&emb_W[((size_t)(n * kM + m)) * kD + d];
        acc.x += xv * w.x; acc.y += xv * w.y; acc.z += xv * w.z; acc.w += xv * w.w;
      }
      float ang0 = (float)b * expf((float)c * c1);
      float ang1 = (float)b * expf((float)(c + 2) * c1);
      acc.x += sinf(ang0); acc.y += cosf(ang0);
      acc.z += sinf(ang1); acc.w += cosf(ang1);
      *(float4*)&hb[(size_t)p * kND + c] = acc;
      union { bf16 h4[4]; uint2 v; } pk;
      pk.h4[0] = __float2bfloat16(acc.x); pk.h4[1] = __float2bfloat16(acc.y);
      pk.h4[2] = __float2bfloat16(acc.z); pk.h4[3] = __float2bfloat16(acc.w);
      *(uint2*)&hbb[(size_t)p * kND + c] = pk.v;
    }
  } else if (bid < OFF_SPK) {
    // ---- spatial Wq -> spW rows [0,128) ----
    int idx = bid - OFF_SPQ;
    int l = idx / 192, rem = idx % 192;
    int hh = rem / 24, n = rem % 24;
    const float* src = sp_Wq + ((((size_t)l * kH + hh) * kN + n)) * (kD * kF);
    bf16* dst = spW + (((size_t)(l * 24 + n)) * 768 + hh * 16) * 128;
    spw_transpose_body(src, dst, (float*)sm, tid);
  } else if (bid < OFF_SPV) {
    // ---- spatial Wk -> spW rows [128,256) ----
    int idx = bid - OFF_SPK;
    int l = idx / 192, rem = idx % 192;
    int hh = rem / 24, n = rem % 24;
    const float* src = sp_Wk + (((size_t)l * kH + hh)) * (kD * kF);
    bf16* dst = spW + (((size_t)(l * 24 + n)) * 768 + 128 + hh * 16) * 128;
    spw_transpose_body(src, dst, (float*)sm, tid);
  } else if (bid < OFF_TMP) {
    // ---- spatial Wv -> spW rows [256,384) ----
    int idx = bid - OFF_SPV;
    int l = idx / 192, rem = idx % 192;
    int hh = rem / 24, n = rem % 24;
    const float* src = sp_Wv + (((size_t)l * kH + hh)) * (kD * kF);
    bf16* dst = spW + (((size_t)(l * 24 + n)) * 768 + 256 + hh * 16) * 128;
    spw_transpose_body(src, dst, (float*)sm, tid);
  } else if (bid < OFF_CVT) {
    // ---- temporal Win -> spW rows [384,768): contiguous cvt per (l,n) ----
    long j8 = ((long)(bid - OFF_TMP) * 256 + tid) * 8;   // over L*24*49152
    long ln = j8 / 49152, rem = j8 % 49152;
    const float* src = &tmp_Win[ln * 49152 + rem];
    float4 v0 = *(const float4*)src, v1 = *(const float4*)(src + 4);
    union { bf16 h[8]; uint4 v; } pk;
    pk.h[0] = __float2bfloat16(v0.x); pk.h[1] = __float2bfloat16(v0.y);
    pk.h[2] = __float2bfloat16(v0.z); pk.h[3] = __float2bfloat16(v0.w);
    pk.h[4] = __float2bfloat16(v1.x); pk.h[5] = __float2bfloat16(v1.y);
    pk.h[6] = __float2bfloat16(v1.z); pk.h[7] = __float2bfloat16(v1.w);
    *(uint4*)&spW[ln * 98304 + 49152 + rem] = pk.v;
  } else if (bid < OFF_SPB) {
    // ---- cvt toWb ----
    int i8 = ((bid - OFF_CVT) * 256 + tid) * 8;
    float4 v0 = *(const float4*)(tmp_Wout + i8);
    float4 v1 = *(const float4*)(tmp_Wout + i8 + 4);
    union { bf16 h[8]; uint4 v; } pk;
    pk.h[0] = __float2bfloat16(v0.x); pk.h[1] = __float2bfloat16(v0.y);
    pk.h[2] = __float2bfloat16(v0.z); pk.h[3] = __float2bfloat16(v0.w);
    pk.h[4] = __float2bfloat16(v1.x); pk.h[5] = __float2bfloat16(v1.y);
    pk.h[6] = __float2bfloat16(v1.z); pk.h[7] = __float2bfloat16(v1.w);
    *(uint4*)(toWb + i8) = pk.v;
  } else if (bid < OFF_W1) {
    // ---- build_spb ----
    int i = (bid - OFF_SPB) * 256 + tid;
    int r = i % 768;
    int n = (i / 768) % 24;
    int l = i / (768 * 24);
    int hh = (r & 127) >> 4, f = r & 15;
    float v;
    if (r < 128)      v = sp_bq[(((size_t)l * kH + hh) * kN + n) * kF + f];
    else if (r < 256) v = sp_bk[((size_t)l * kH + hh) * kF + f];
    else if (r < 384) v = sp_bv[((size_t)l * kH + hh) * kF + f];
    else              v = tmp_bin[((size_t)l * kN + n) * 384 + (r - 384)];
    spbc[i] = v;
  } else if (bid < OFF_W2) {
    // ---- trans_cvt W1: fp32 (kND x kFF) -> bf16 (kFF x kND), per l ----
    int id2 = bid - OFF_W1;
    int bz = id2 / (16 * 48);
    int rem = id2 % (16 * 48);
    trans_cvt_body(ff_W1 + (size_t)bz * kND * kFF, W1t + (size_t)bz * kFF * kND,
                   kND, kFF, rem % 16, rem / 16, (float(*)[65])sm, tid);
  } else if (bid < OFF_FIN) {
    // ---- trans_cvt W2: fp32 (kFF x kND) -> bf16 (kND x kFF), per l ----
    int id2 = bid - OFF_W2;
    int bz = id2 / (48 * 16);
    int rem = id2 % (48 * 16);
    trans_cvt_body(ff_W2 + (size_t)bz * kFF * kND, W2t + (size_t)bz * kND * kFF,
                   kFF, kND, rem % 48, rem / 48, (float(*)[65])sm, tid);
  } else {
    // ---- trans_cvt fin_W: fp32 (kND x kNM) -> bf16 (kNM x kND) ----
    int id2 = bid - OFF_FIN;
    trans_cvt_body(fin_W, finWt, kND, kNM, id2 % 4, id2 / 4, (float(*)[65])sm, tid);
  }
}

// ---------------------------------------------------------------------------
// Spatial attention — float4 LDS traffic throughout. (Separate dispatch:
// r5 proved fusing with t_attn inherits its 148 VGPR -> 2 blocks/CU cap.)
// ---------------------------------------------------------------------------
__global__ __launch_bounds__(192) void sp_attn_kernel(
    const bf16* __restrict__ qkv, float* __restrict__ out)
{
  int p = blockIdx.x;
  __shared__ float s[24 * 388];
  for (int i = threadIdx.x; i < 2304; i += 192) {
    int n = i / 96, c4 = (i % 96) * 4;
    ushort4 u = *(const ushort4*)((const ushort*)qkv + ((size_t)n * kP + p) * 768 + c4);
    float4 f;
    f.x = __bfloat162float(*(const bf16*)&u.x);
    f.y = __bfloat162float(*(const bf16*)&u.y);
    f.z = __bfloat162float(*(const bf16*)&u.z);
    f.w = __bfloat162float(*(const bf16*)&u.w);
    *(float4*)&s[n * 388 + c4] = f;
  }
  __syncthreads();
  int hh = threadIdx.x / 24, n = threadIdx.x % 24;
  const float4* qr = (const float4*)(s + n * 388 + hh * 16);
  float4 q0 = qr[0], q1 = qr[1], q2 = qr[2], q3 = qr[3];
  float sc[24];
  float mx = -1e30f;
#pragma unroll
  for (int m = 0; m < 24; m++) {
    const float4* kr = (const float4*)(s + m * 388 + 128 + hh * 16);
    float4 k0 = kr[0], k1 = kr[1], k2 = kr[2], k3 = kr[3];
    float d = q0.x * k0.x + q0.y * k0.y + q0.z * k0.z + q0.w * k0.w
            + q1.x * k1.x + q1.y * k1.y + q1.z * k1.z + q1.w * k1.w
            + q2.x * k2.x + q2.y * k2.y + q2.z * k2.z + q2.w * k2.w
            + q3.x * k3.x + q3.y * k3.y + q3.z * k3.z + q3.w * k3.w;
    d *= 0.25f;
    sc[m] = d;
    mx = fmaxf(mx, d);
  }
  float sum = 0.f;
#pragma unroll
  for (int m = 0; m < 24; m++) { float e = __expf(sc[m] - mx); sc[m] = e; sum += e; }
  float inv = 1.f / sum;
  float4 o0 = {0,0,0,0}, o1 = {0,0,0,0}, o2 = {0,0,0,0}, o3 = {0,0,0,0};
#pragma unroll
  for (int m = 0; m < 24; m++) {
    const float4* vr = (const float4*)(s + m * 388 + 256 + hh * 16);
    float4 v0 = vr[0], v1 = vr[1], v2 = vr[2], v3 = vr[3];
    float w = sc[m];
    o0.x += w * v0.x; o0.y += w * v0.y; o0.z += w * v0.z; o0.w += w * v0.w;
    o1.x += w * v1.x; o1.y += w * v1.y; o1.z += w * v1.z; o1.w += w * v1.w;
    o2.x += w * v2.x; o2.y += w * v2.y; o2.z += w * v2.z; o2.w += w * v2.w;
    o3.x += w * v3.x; o3.y += w * v3.y; o3.z += w * v3.z; o3.w += w * v3.w;
  }
  float* orow = out + (size_t)p * kND + n * kD + hh * 16;
  o0.x *= inv; o0.y *= inv; o0.z *= inv; o0.w *= inv;
  o1.x *= inv; o1.y *= inv; o1.z *= inv; o1.w *= inv;
  o2.x *= inv; o2.y *= inv; o2.z *= inv; o2.w *= inv;
  o3.x *= inv; o3.y *= inv; o3.z *= inv; o3.w *= inv;
  *(float4*)(orow)      = o0;
  *(float4*)(orow + 4)  = o1;
  *(float4*)(orow + 8)  = o2;
  *(float4*)(orow + 12) = o3;
}

// ---------------------------------------------------------------------------
// Temporal attention via MFMA, one block per (b,n,h), 128 threads (2 waves).
// Ps ALIASES the dead Qs/Ks region (r5-verified): LDS 59.9 KB -> 39.2 KB,
// occupancy 2 -> 4 blocks/CU (now VGPR-capped, not LDS-capped).
// ---------------------------------------------------------------------------
__global__ __launch_bounds__(128) void t_attn_mfma(
    const bf16* __restrict__ qkv, bf16* __restrict__ ot)
{
  int g = blockIdx.x;
  int hh = g & 7, n = (g >> 3) % 24, b = g / 192;
  __shared__ __align__(16) char smem[39168];
  ushort (*Qs)[40]  = (ushort(*)[40])(smem);            // [0,10240)
  ushort (*Ks)[40]  = (ushort(*)[40])(smem + 10240);    // [10240,20480)
  ushort (*Ps)[136] = (ushort(*)[136])(smem);           // [0,34816) aliases Qs/Ks
  ushort (*Vt)[136] = (ushort(*)[136])(smem + 34816);   // [34816,39168)

  for (int idx = threadIdx.x; idx < 256; idx += 128) {
    int t = idx >> 1, e8 = (idx & 1) * 8;
    const ushort* src = (const ushort*)qkv +
        ((size_t)n * kP + (size_t)t * kB + b) * 768 + 384 + hh * 16 + e8;
    uint4 q = *(const uint4*)(src);
    uint4 k = *(const uint4*)(src + 128);
    uint4 v = *(const uint4*)(src + 256);
    *(uint4*)&Qs[t][e8] = q;
    *(uint4*)&Ks[t][e8] = k;
    *(uint4*)&Qs[t][16 + e8] = make_uint4(0, 0, 0, 0);
    *(uint4*)&Ks[t][16 + e8] = make_uint4(0, 0, 0, 0);
    const ushort* vp = (const ushort*)&v;
#pragma unroll
    for (int j = 0; j < 8; j++) Vt[e8 + j][t] = vp[j];
  }
  __syncthreads();

  int lane = threadIdx.x & 63, w = threadIdx.x >> 6;
  int c = lane & 15, quad = lane >> 4;

  // S = Q K^T (Qs/Ks fully consumed into registers here)
  bf16x8 aq[4];
#pragma unroll
  for (int mt = 0; mt < 4; mt++)
    aq[mt] = *(const bf16x8*)&Qs[w * 64 + mt * 16 + c][quad * 8];
  f32x4 acc[4][8];
#pragma unroll
  for (int nt = 0; nt < 8; nt++) {
    bf16x8 bk = *(const bf16x8*)&Ks[nt * 16 + c][quad * 8];
#pragma unroll
    for (int mt = 0; mt < 4; mt++) {
      f32x4 z = {0.f, 0.f, 0.f, 0.f};
      acc[mt][nt] = __builtin_amdgcn_mfma_f32_16x16x32_bf16(aq[mt], bk, z, 0, 0, 0);
    }
  }
  __syncthreads();   // Qs/Ks dead -> Ps may overwrite

  // softmax per row; rows t = w*64 + mt*16 + quad*4 + r, cols s = nt*16 + c
  f32x4 invv[4];
#pragma unroll
  for (int mt = 0; mt < 4; mt++) {
    int tbase = w * 64 + mt * 16 + quad * 4;
    f32x4 rm = {-1e30f, -1e30f, -1e30f, -1e30f};
#pragma unroll
    for (int nt = 0; nt < 8; nt++) {
      int s = nt * 16 + c;
#pragma unroll
      for (int r = 0; r < 4; r++) {
        float x = acc[mt][nt][r] * 0.25f + ((s < tbase + r) ? 1.f : 0.f);
        acc[mt][nt][r] = x;
        rm[r] = fmaxf(rm[r], x);
      }
    }
#pragma unroll
    for (int off = 1; off < 16; off <<= 1)
#pragma unroll
      for (int r = 0; r < 4; r++) rm[r] = fmaxf(rm[r], __shfl_xor(rm[r], off, 64));
    f32x4 rs = {0.f, 0.f, 0.f, 0.f};
#pragma unroll
    for (int nt = 0; nt < 8; nt++)
#pragma unroll
      for (int r = 0; r < 4; r++) {
        float pp = __expf(acc[mt][nt][r] - rm[r]);
        acc[mt][nt][r] = pp;
        rs[r] += pp;
      }
#pragma unroll
    for (int off = 1; off < 16; off <<= 1)
#pragma unroll
      for (int r = 0; r < 4; r++) rs[r] += __shfl_xor(rs[r], off, 64);
#pragma unroll
    for (int r = 0; r < 4; r++) invv[mt][r] = 1.f / rs[r];
#pragma unroll
    for (int nt = 0; nt < 8; nt++)
#pragma unroll
      for (int r = 0; r < 4; r++) {
        bf16 pb = __float2bfloat16(acc[mt][nt][r]);
        Ps[tbase + r][nt * 16 + c] = *(ushort*)&pb;
      }
  }

  // O = P V (in-wave Ps reuse only)
  f32x4 o[4] = {};
#pragma unroll
  for (int ks = 0; ks < 128; ks += 32) {
    bf16x8 bv = *(const bf16x8*)&Vt[c][ks + quad * 8];
#pragma unroll
    for (int mt = 0; mt < 4; mt++) {
      bf16x8 ap = *(const bf16x8*)&Ps[w * 64 + mt * 16 + c][ks + quad * 8];
      o[mt] = __builtin_amdgcn_mfma_f32_16x16x32_bf16(ap, bv, o[mt], 0, 0, 0);
    }
  }

#pragma unroll
  for (int mt = 0; mt < 4; mt++) {
#pragma unroll
    for (int r = 0; r < 4; r++) {
      int t = w * 64 + mt * 16 + quad * 4 + r;
      float val = o[mt][r] * invv[mt][r];
      ot[((size_t)n * kP + (size_t)t * kB + b) * 128 + hh * 16 + c] = __float2bfloat16(val);
    }
  }
}

// ---------------------------------------------------------------------------
// Fused: a2 = LN(sp+h) + LN(tp+h); float4 traffic; writes a2 fp32 + bf16
// ---------------------------------------------------------------------------
__global__ __launch_bounds__(256) void fuse_a2_kernel(
    const float* __restrict__ sp, const float* __restrict__ tp,
    const float* __restrict__ h, const float* __restrict__ g,
    const float* __restrict__ be, float* __restrict__ a2, bf16* __restrict__ a2b)
{
  int row = blockIdx.x;
  const float4* s1p = (const float4*)(sp + (size_t)row * kND);
  const float4* s2p = (const float4*)(tp + (size_t)row * kND);
  const float4* hp  = (const float4*)(h  + (size_t)row * kND);
  float4 x1[3], x2[3];
  float sum1 = 0.f, sum2 = 0.f;
#pragma unroll
  for (int i = 0; i < 3; i++) {
    int c = threadIdx.x + 256 * i;
    float4 hv = hp[c], a = s1p[c], bb = s2p[c];
    a.x += hv.x; a.y += hv.y; a.z += hv.z; a.w += hv.w;
    bb.x += hv.x; bb.y += hv.y; bb.z += hv.z; bb.w += hv.w;
    x1[i] = a; x2[i] = bb;
    sum1 += a.x + a.y + a.z + a.w;
    sum2 += bb.x + bb.y + bb.z + bb.w;
  }
  __shared__ float red1[4], red2[4];
#pragma unroll
  for (int o = 32; o > 0; o >>= 1) { sum1 += __shfl_down(sum1, o, 64); sum2 += __shfl_down(sum2, o, 64); }
  int wid = threadIdx.x >> 6;
  if ((threadIdx.x & 63) == 0) { red1[wid] = sum1; red2[wid] = sum2; }
  __syncthreads();
  float mean1 = (red1[0] + red1[1] + red1[2] + red1[3]) * (1.f / kND);
  float mean2 = (red2[0] + red2[1] + red2[2] + red2[3]) * (1.f / kND);
  __syncthreads();
  float v1 = 0.f, v2 = 0.f;
#pragma unroll
  for (int i = 0; i < 3; i++) {
    float4 a = x1[i], bb = x2[i];
    v1 += (a.x - mean1) * (a.x - mean1) + (a.y - mean1) * (a.y - mean1)
        + (a.z - mean1) * (a.z - mean1) + (a.w - mean1) * (a.w - mean1);
    v2 += (bb.x - mean2) * (bb.x - mean2) + (bb.y - mean2) * (bb.y - mean2)
        + (bb.z - mean2) * (bb.z - mean2) + (bb.w - mean2) * (bb.w - mean2);
  }
#pragma unroll
  for (int o = 32; o > 0; o >>= 1) { v1 += __shfl_down(v1, o, 64); v2 += __shfl_down(v2, o, 64); }
  if ((threadIdx.x & 63) == 0) { red1[wid] = v1; red2[wid] = v2; }
  __syncthreads();
  float r1 = rsqrtf((red1[0] + red1[1] + red1[2] + red1[3]) * (1.f / kND) + 1e-5f);
  float r2 = rsqrtf((red2[0] + red2[1] + red2[2] + red2[3]) * (1.f / kND) + 1e-5f);
  const float4* g4 = (const float4*)g;
  const float4* b4 = (const float4*)be;
#pragma unroll
  for (int i = 0; i < 3; i++) {
    int c = threadIdx.x + 256 * i;
    float4 gc = g4[c], bc = b4[c];
    float4 a = x1[i], bb = x2[i], o;
    o.x = (a.x - mean1) * r1 * gc.x + bc.x + (bb.x - mean2) * r2 * gc.x + bc.x;
    o.y = (a.y - mean1) * r1 * gc.y + bc.y + (bb.y - mean2) * r2 * gc.y + bc.y;
    o.z = (a.z - mean1) * r1 * gc.z + bc.z + (bb.z - mean2) * r2 * gc.z + bc.z;
    o.w = (a.w - mean1) * r1 * gc.w + bc.w + (bb.w - mean2) * r2 * gc.w + bc.w;
    *(float4*)(a2 + (size_t)row * kND + c * 4) = o;
    union { bf16 h4[4]; uint2 v; } pk;
    pk.h4[0] = __float2bfloat16(o.x); pk.h4[1] = __float2bfloat16(o.y);
    pk.h4[2] = __float2bfloat16(o.z); pk.h4[3] = __float2bfloat16(o.w);
    *(uint2*)(a2b + (size_t)row * kND + c * 4) = pk.v;
  }
}

// out = LN(a + b); float4 traffic; writes fp32 + bf16
__global__ __launch_bounds__(256) void add_ln_dual_kernel(
    const float* __restrict__ a, const float* __restrict__ b,
    const float* __restrict__ g, const float* __restrict__ be,
    float* __restrict__ out, bf16* __restrict__ outb)
{
  int row = blockIdx.x;
  const float4* ar = (const float4*)(a + (size_t)row * kND);
  const float4* br = (const float4*)(b + (size_t)row * kND);
  float4 v[3];
  float s = 0.f;
#pragma unroll
  for (int i = 0; i < 3; i++) {
    int c = threadIdx.x + 256 * i;
    float4 x = ar[c], y = br[c];
    x.x += y.x; x.y += y.y; x.z += y.z; x.w += y.w;
    v[i] = x;
    s += x.x + x.y + x.z + x.w;
  }
  __shared__ float red[4];
#pragma unroll
  for (int o = 32; o > 0; o >>= 1) s += __shfl_down(s, o, 64);
  int wid = threadIdx.x >> 6;
  if ((threadIdx.x & 63) == 0) red[wid] = s;
  __syncthreads();
  float mean = (red[0] + red[1] + red[2] + red[3]) * (1.f / kND);
  __syncthreads();
  float vs = 0.f;
#pragma unroll
  for (int i = 0; i < 3; i++) {
    float4 x = v[i];
    vs += (x.x - mean) * (x.x - mean) + (x.y - mean) * (x.y - mean)
        + (x.z - mean) * (x.z - mean) + (x.w - mean) * (x.w - mean);
  }
#pragma unroll
  for (int o = 32; o > 0; o >>= 1) vs += __shfl_down(vs, o, 64);
  if ((threadIdx.x & 63) == 0) red[wid] = vs;
  __syncthreads();
  float rstd = rsqrtf((red[0] + red[1] + red[2] + red[3]) * (1.f / kND) + 1e-5f);
  const float4* g4 = (const float4*)g;
  const float4* b4 = (const float4*)be;
#pragma unroll
  for (int i = 0; i < 3; i++) {
    int c = threadIdx.x + 256 * i;
    float4 gc = g4[c], bc = b4[c], x = v[i], o;
    o.x = (x.x - mean) * rstd * gc.x + bc.x;
    o.y = (x.y - mean) * rstd * gc.y + bc.y;
    o.z = (x.z - mean) * rstd * gc.z + bc.z;
    o.w = (x.w - mean) * rstd * gc.w + bc.w;
    *(float4*)(out + (size_t)row * kND + c * 4) = o;
    union { bf16 h4[4]; uint2 v2; } pk;
    pk.h4[0] = __float2bfloat16(o.x); pk.h4[1] = __float2bfloat16(o.y);
    pk.h4[2] = __float2bfloat16(o.z); pk.h4[3] = __float2bfloat16(o.w);
    *(uint2*)(outb + (size_t)row * kND + c * 4) = pk.v2;
  }
}

// Final: out[b,t,c] = sum_z part[z][(t*B+b)*216+c] + fin_b[c] + inputs[b,t,c]
__global__ __launch_bounds__(256) void final_reduce_add_kernel(
    const float* __restrict__ part, const float* __restrict__ fin_b,
    const float* __restrict__ inp, float* __restrict__ out)
{
  int i = blockIdx.x * 256 + threadIdx.x;
  if (i >= kB * kT * kNM) return;
  int c = i % kNM;
  int rem = i / kNM;
  int t = rem % kT, b = rem / kT;
  size_t pi = (size_t)(t * kB + b) * kNM + c;
  const size_t S = (size_t)kP * kNM;
  float v = fin_b[c] + inp[i];
#pragma unroll
  for (int z = 0; z < 8; z++) v += part[z * S + pi];
  out[i] = v;
}

// ---------------------------------------------------------------------------
extern "C" void kernel_launch(void* const* d_in, const int* in_sizes, int n_in,
                              void* d_out, int out_size, void* d_ws, size_t ws_size,
                              hipStream_t stream)
{
  const float* inputs   = (const float*)d_in[0];
  const float* emb_W    = (const float*)d_in[1];
  const float* emb_b    = (const float*)d_in[2];
  const float* sp_Wq    = (const float*)d_in[3];
  const float* sp_bq    = (const float*)d_in[4];
  const float* sp_Wk    = (const float*)d_in[5];
  const float* sp_bk    = (const float*)d_in[6];
  const float* sp_Wv    = (const float*)d_in[7];
  const float* sp_bv    = (const float*)d_in[8];
  const float* tmp_Win  = (const float*)d_in[9];
  const float* tmp_bin  = (const float*)d_in[10];
  const float* tmp_Wout = (const float*)d_in[11];
  const float* tmp_bout = (const float*)d_in[12];
  const float* ff_W1    = (const float*)d_in[13];
  const float* ff_b1    = (const float*)d_in[14];
  const float* ff_W2    = (const float*)d_in[15];
  const float* ff_b2    = (const float*)d_in[16];
  const float* ln_g     = (const float*)d_in[17];
  const float* ln_b     = (const float*)d_in[18];
  const float* fin_W    = (const float*)d_in[19];
  const float* fin_b    = (const float*)d_in[20];
  float* out = (float*)d_out;

  // ---- workspace layout ----
  char* wp = (char*)d_ws;
  size_t off = 0;
  auto alloc = [&](size_t bytes) { void* p = wp + off; off += (bytes + 255) & ~(size_t)255; return p; };
  bf16* spW   = (bf16*)alloc((size_t)kL * 24 * 768 * 128 * 2);  // fused qkv weights
  bf16* toWb  = (bf16*)alloc((size_t)kL * 24 * 128 * 128 * 2);
  bf16* W1t   = (bf16*)alloc((size_t)kL * kFF * kND * 2);
  bf16* W2t   = (bf16*)alloc((size_t)kL * kND * kFF * 2);
  bf16* finWt = (bf16*)alloc((size_t)kNM * kND * 2);
  float* spbc = (float*)alloc((size_t)kL * 24 * 768 * 4);
  float* hb   = (float*)alloc((size_t)kP * kND * 4);
  bf16*  hbb  = (bf16*) alloc((size_t)kP * kND * 2);
  bf16*  qkvb = (bf16*) alloc((size_t)24 * kP * 768 * 2);   // fused spatial+temporal qkv
  float* sp   = (float*)alloc((size_t)kP * kND * 4);        // spatial out; FF1 partials
  float* tp   = (float*)alloc((size_t)kP * kND * 4);        // temporal out; FF2 out; final partials
  float* a2   = (float*)alloc((size_t)kP * kND * 4);
  bf16*  a2b  = (bf16*) alloc((size_t)kP * kND * 2);
  bf16*  otb  = (bf16*) alloc((size_t)24 * kP * 128 * 2);
  float* ffpart  = sp;   // 3 * kP*kFF fp32 = 12 MB (sp dead during FF)
  float* finpart = tp;   // 8 * kP*kNM fp32 = 6.9 MB (tp dead after loop)

  // ---- all weight prep + embedding: ONE dispatch ----
  prep_kernel<<<NB_PREP, 256, 0, stream>>>(
      sp_Wq, sp_Wk, sp_Wv, tmp_Win, spW,
      tmp_Wout, toWb,
      sp_bq, sp_bk, sp_bv, tmp_bin, spbc,
      ff_W1, W1t, ff_W2, W2t, fin_W, finWt,
      inputs, emb_W, emb_b, hb, hbb);

  for (int l = 0; l < kL; l++) {
    const float* lg = ln_g + (size_t)l * kND;
    const float* lb = ln_b + (size_t)l * kND;

    // fused spatial+temporal qkv: groups n; C = qkvb (n, p, 768) bf16
    mfma_gemm<128, 128, true><<<dim3(6, 8, 24), 256, 0, stream>>>(
        hbb, spW + (size_t)l * 24 * 768 * 128, spbc + (size_t)l * 24 * 768, qkvb,
        kP, 768, 128, /*ldB*/128, /*sAi*/kND, /*sCi*/768,
        /*offAg*/128, /*offBg*/768 * 128, /*offCg*/(long)kP * 768, /*sBg*/768);

    sp_attn_kernel<<<kP, 192, 0, stream>>>(qkvb, sp);
    t_attn_mfma<<<kB * 24 * 8, 128, 0, stream>>>(qkvb, otb);

    // temporal out-proj: 64x64 tiles -> 768 blocks
    mfma_gemm<64, 64, false><<<dim3(2, 16, 24), 256, 0, stream>>>(
        otb, toWb + (size_t)l * 24 * 128 * 128, tmp_bout + (size_t)l * 24 * 128, tp,
        kP, 128, 128, /*ldB*/128, /*sAi*/128, /*sCi*/kND,
        /*offAg*/(long)kP * 128, /*offBg*/128 * 128, /*offCg*/128, /*sBg*/128);

    fuse_a2_kernel<<<kP, 256, 0, stream>>>(sp, tp, hb, lg, lb, a2, a2b);

    // FF1 split-K=3: 768 blocks, K-chunk 1024, fp32 partials -> ffpart
    mfma_gemm<64, 64, false><<<dim3(kFF / 64, kP / 64, 3), 256, 0, stream>>>(
        a2b, W1t + (size_t)l * kFF * kND, nullptr, ffpart,
        kP, kFF, /*K*/kND / 3, /*ldB*/kND, /*sAi*/kND, /*sCi*/kFF,
        /*offAg*/kND / 3, /*offBg*/kND / 3, /*offCg*/(long)kP * kFF, /*sBg*/0);

    // FF2 with fused ff1-reduce A-staging (AMODE=1): A = sum of 3 partials + ff_b1
    mfma_gemm<64, 64, false, 1><<<dim3(kND / 64, kP / 64, 1), 256, 0, stream>>>(
        nullptr, W2t + (size_t)l * kND * kFF, ff_b2 + (size_t)l * kND, tp,
        kP, kND, kFF, /*ldB*/kFF, /*sAi*/0, /*sCi*/kND, 0, 0, 0, 0,
        ffpart, ff_b1 + (size_t)l * kFF);

    add_ln_dual_kernel<<<kP, 256, 0, stream>>>(tp, a2, lg, lb, hb, hbb);
  }

  // final projection: split-K=8 (K-chunk 384) -> 512 blocks; fused reduce+residual
  mfma_gemm<64, 64, false><<<dim3((kNM + 63) / 64, kP / 64, 8), 256, 0, stream>>>(
      hbb, finWt, nullptr, finpart,
      kP, kNM, /*K*/kND / 8, /*ldB*/kND, /*sAi*/kND, /*sCi*/kNM,
      /*offAg*/kND / 8, /*offBg*/kND / 8, /*offCg*/(long)kP * kNM, /*sBg*/0);
  final_reduce_add_kernel<<<(kB * kT * kNM + 255) / 256, 256, 0, stream>>>(
      finpart, fin_b, inputs, out);
}

// Round 7
// 762.970 us; speedup vs baseline: 1.1591x; 1.1063x over previous
//
#include <hip/hip_runtime.h>
#include <hip/hip_bf16.h>
#include <math.h>

// Problem constants
constexpr int kB = 8, kT = 128, kN = 24, kD = 128, kM = 9, kH = 8, kL = 4, kFF = 1024;
constexpr int kF = 16;          // D/H
constexpr int kHD = 16;         // D/H
constexpr int kND = kN * kD;    // 3072
constexpr int kNM = kN * kM;    // 216
constexpr int kP = kB * kT;     // 1024 tokens, p = t*B + b

using bf16x8 = __attribute__((ext_vector_type(8))) short;
using f32x4  = __attribute__((ext_vector_type(4))) float;
typedef __hip_bfloat16 bf16;

__device__ __forceinline__ void load_lds16(const void* g, void* l) {
  __builtin_amdgcn_global_load_lds(
      (const __attribute__((address_space(1))) void*)g,
      (__attribute__((address_space(3))) void*)l, 16, 0, 0);
}

// ---------------------------------------------------------------------------
// MFMA bf16 GEMM, BK=64, XOR-swizzled LDS (conflict-free b128 fragment reads,
// wave-contiguous global_load_lds staging). Exact r4 version (AMODE fusion
// reverted: r6 showed in-loop reduce staging costs ~17 µs/layer).
// ---------------------------------------------------------------------------
template<int BM, int BN, bool OUTBF>
__global__ __launch_bounds__(256) void mfma_gemm(
    const bf16* __restrict__ A, const bf16* __restrict__ Bm,
    const float* __restrict__ bias, void* __restrict__ Cv,
    int M, int Nc, int K, int ldB, int sAi, int sCi,
    long offAg, long offBg, long offCg, int sBg)
{
  constexpr int WM = BM / 2, WN = BN / 2;
  constexpr int MT = WM / 16, NT = WN / 16;
  constexpr int ASLOTS = BM * 8;   // 16-B slots (BM rows x 128 B per k-chunk)
  constexpr int BSLOTS = BN * 8;
  constexpr int CSTR = BN + 4;     // repack stride (floats)
  __shared__ __align__(16) char smem[(BM + BN) * 64 * 2];
  bf16* As = (bf16*)smem;
  bf16* Bs = (bf16*)(smem + BM * 64 * 2);
  float* Cs = (float*)smem;        // epilogue repack area

  int g = blockIdx.z;
  A  += offAg * g;
  Bm += offBg * g;
  long cbase = offCg * (long)g;
  int bOff = sBg * g;

  int m0 = blockIdx.y * BM, n0 = blockIdx.x * BN;
  int tid = threadIdx.x, lane = tid & 63, wave = tid >> 6;
  int wm = wave >> 1, wn = wave & 1;
  int fr = lane & 15, fq = lane >> 4;

  f32x4 acc[MT][NT] = {};

  for (int kk = 0; kk < K; kk += 64) {
#pragma unroll
    for (int s = tid; s < ASLOTS; s += 256) {
      int m = s >> 3, kq = (s & 7) ^ (m & 7);     // XOR swizzle
      load_lds16(A + (size_t)(m0 + m) * sAi + (kk + kq * 8), &As[s * 8]);
    }
#pragma unroll
    for (int s = tid; s < BSLOTS; s += 256) {
      int n = s >> 3, kq = (s & 7) ^ (n & 7);
      int nr = n0 + n; if (nr > Nc - 1) nr = Nc - 1;   // clamp ragged N
      load_lds16(Bm + (size_t)nr * ldB + (kk + kq * 8), &Bs[s * 8]);
    }
    __syncthreads();
#pragma unroll
    for (int ks = 0; ks < 2; ks++) {
      bf16x8 af[MT], bfr[NT];
#pragma unroll
      for (int i = 0; i < MT; i++) {
        int row = wm * WM + i * 16 + fr;
        af[i] = *(const bf16x8*)&As[row * 64 + (((ks * 4 + fq) ^ (row & 7)) * 8)];
      }
#pragma unroll
      for (int j = 0; j < NT; j++) {
        int row = wn * WN + j * 16 + fr;
        bfr[j] = *(const bf16x8*)&Bs[row * 64 + (((ks * 4 + fq) ^ (row & 7)) * 8)];
      }
#pragma unroll
      for (int i = 0; i < MT; i++)
#pragma unroll
        for (int j = 0; j < NT; j++)
          acc[i][j] = __builtin_amdgcn_mfma_f32_16x16x32_bf16(af[i], bfr[j], acc[i][j], 0, 0, 0);
    }
    __syncthreads();
  }

  // ---- epilogue: per m-tile round, repack 32 rows x BN through LDS ----
  constexpr int NCHUNK = BN / 16;
  int tcol = tid & (NCHUNK - 1);
  int trow = tid / NCHUNK;          // row within the 32-row round
  int colbase = n0 + tcol * 16;
  float vb[16];
  if (trow < 32) {
#pragma unroll
    for (int jj = 0; jj < 16; jj++)
      vb[jj] = bias ? bias[bOff + colbase + jj] : 0.f;
  }
#pragma unroll
  for (int i = 0; i < MT; i++) {
    __syncthreads();
#pragma unroll
    for (int j = 0; j < NT; j++)
#pragma unroll
      for (int r = 0; r < 4; r++)
        Cs[(wm * 16 + fq * 4 + r) * CSTR + wn * WN + j * 16 + fr] = acc[i][j][r];
    __syncthreads();
    if (trow < 32) {
      int row = m0 + (trow >> 4) * WM + i * 16 + (trow & 15);
      float vals[16];
#pragma unroll
      for (int jj = 0; jj < 4; jj++)
        *(float4*)&vals[jj * 4] = *(const float4*)&Cs[trow * CSTR + tcol * 16 + jj * 4];
#pragma unroll
      for (int jj = 0; jj < 16; jj++) vals[jj] += vb[jj];
      if (OUTBF) {
        bf16* cp = (bf16*)Cv + cbase + (size_t)row * sCi + colbase;
        union { bf16 h[8]; uint4 v; } pk;
#pragma unroll
        for (int half = 0; half < 2; half++) {
          if (colbase + half * 8 + 8 <= Nc) {
#pragma unroll
            for (int jj = 0; jj < 8; jj++) pk.h[jj] = __float2bfloat16(vals[half * 8 + jj]);
            *(uint4*)(cp + half * 8) = pk.v;
          }
        }
      } else {
        float* cp = (float*)Cv + cbase + (size_t)row * sCi + colbase;
#pragma unroll
        for (int jj = 0; jj < 4; jj++)
          if (colbase + jj * 4 + 4 <= Nc) *(float4*)(cp + jj * 4) = *(float4*)&vals[jj * 4];
      }
    }
  }
}

// ---------------------------------------------------------------------------
// Mega prep kernel: all weight prep + embedding in ONE dispatch.
// ---------------------------------------------------------------------------
constexpr int NB_EMB = kP;                                     // 1024
constexpr int NB_SPQ = kL * kH * kN;                           // 768
constexpr int NB_SPK = kL * kH * kN;                           // 768
constexpr int NB_SPV = kL * kH * kN;                           // 768
constexpr int NB_TMP = (kL * kN * 384 * kD / 8) / 256;         // 2304
constexpr int NB_CVT = (kL * 24 * 128 * 128 / 8) / 256;        // 768
constexpr int NB_SPB = (kL * 24 * 768) / 256;                  // 288
constexpr int NB_W1  = (kFF / 64) * (kND / 64) * kL;           // 3072
constexpr int NB_W2  = (kND / 64) * (kFF / 64) * kL;           // 3072
constexpr int NB_FIN = ((kNM + 63) / 64) * (kND / 64);         // 192
constexpr int OFF_SPQ = NB_EMB;
constexpr int OFF_SPK = OFF_SPQ + NB_SPQ;
constexpr int OFF_SPV = OFF_SPK + NB_SPK;
constexpr int OFF_TMP = OFF_SPV + NB_SPV;
constexpr int OFF_CVT = OFF_TMP + NB_TMP;
constexpr int OFF_SPB = OFF_CVT + NB_CVT;
constexpr int OFF_W1  = OFF_SPB + NB_SPB;
constexpr int OFF_W2  = OFF_W1 + NB_W1;
constexpr int OFF_FIN = OFF_W2 + NB_W2;
constexpr int NB_PREP = OFF_FIN + NB_FIN;                      // 13024

__device__ __forceinline__ void trans_cvt_body(
    const float* __restrict__ in, bf16* __restrict__ out,
    int R, int C, int bx, int by, float (*t)[65], int tid)
{
  int c0 = bx * 64, r0 = by * 64;
  for (int s = tid; s < 1024; s += 256) {
    int rr = s >> 4, c4 = (s & 15) * 4;
    int r = r0 + rr, c = c0 + c4;
    float4 v;
    if (c + 4 <= C) v = *(const float4*)&in[(size_t)r * C + c];
    else {
      float tmp[4];
#pragma unroll
      for (int j = 0; j < 4; j++) tmp[j] = (c + j < C) ? in[(size_t)r * C + c + j] : 0.f;
      v = *(float4*)tmp;
    }
    *(float4*)&t[rr][c4] = v;
  }
  __syncthreads();
  for (int s = tid; s < 512; s += 256) {
    int cc = s >> 3, r8 = (s & 7) * 8;
    int c = c0 + cc;
    if (c < C) {
      union { bf16 h[8]; uint4 v; } pk;
#pragma unroll
      for (int j = 0; j < 8; j++) pk.h[j] = __float2bfloat16(t[r8 + j][cc]);
      *(uint4*)&out[(size_t)c * R + r0 + r8] = pk.v;
    }
  }
}

// 128x16 fp32 panel (d-major, f innermost) -> 16 rows x 128 bf16 (d innermost).
__device__ __forceinline__ void spw_transpose_body(
    const float* __restrict__ src, bf16* __restrict__ dst, float* ts, int tid)
{
  for (int s = tid; s < 512; s += 256) {
    float4 v = ((const float4*)src)[s];
    int d = s >> 2, f4 = (s & 3) * 4;
    ts[(f4 + 0) * 132 + d] = v.x;
    ts[(f4 + 1) * 132 + d] = v.y;
    ts[(f4 + 2) * 132 + d] = v.z;
    ts[(f4 + 3) * 132 + d] = v.w;
  }
  __syncthreads();
  int f = tid >> 4, d8 = (tid & 15) * 8;
  float4 a = *(const float4*)&ts[f * 132 + d8];
  float4 b = *(const float4*)&ts[f * 132 + d8 + 4];
  union { bf16 h[8]; uint4 v; } pk;
  pk.h[0] = __float2bfloat16(a.x); pk.h[1] = __float2bfloat16(a.y);
  pk.h[2] = __float2bfloat16(a.z); pk.h[3] = __float2bfloat16(a.w);
  pk.h[4] = __float2bfloat16(b.x); pk.h[5] = __float2bfloat16(b.y);
  pk.h[6] = __float2bfloat16(b.z); pk.h[7] = __float2bfloat16(b.w);
  *(uint4*)&dst[(size_t)f * 128 + d8] = pk.v;
}

__global__ __launch_bounds__(256) void prep_kernel(
    const float* __restrict__ sp_Wq, const float* __restrict__ sp_Wk,
    const float* __restrict__ sp_Wv, const float* __restrict__ tmp_Win,
    bf16* __restrict__ spW,
    const float* __restrict__ tmp_Wout, bf16* __restrict__ toWb,
    const float* __restrict__ sp_bq, const float* __restrict__ sp_bk,
    const float* __restrict__ sp_bv, const float* __restrict__ tmp_bin,
    float* __restrict__ spbc,
    const float* __restrict__ ff_W1, bf16* __restrict__ W1t,
    const float* __restrict__ ff_W2, bf16* __restrict__ W2t,
    const float* __restrict__ fin_W, bf16* __restrict__ finWt,
    const float* __restrict__ inp, const float* __restrict__ emb_W,
    const float* __restrict__ emb_b, float* __restrict__ hb,
    bf16* __restrict__ hbb)
{
  __shared__ __align__(16) char sm[64 * 65 * 4];
  int bid = blockIdx.x, tid = threadIdx.x;

  if (bid < OFF_SPQ) {
    // ---- embedding (latency/transcendental-bound: schedule first) ----
    int p = bid;
    int t = p / kB, b = p % kB;
    float* xs = (float*)sm;
    if (tid < kNM)
      xs[tid] = inp[((size_t)b * kT + t) * kNM + tid];
    __syncthreads();
    const float c1 = -logf(10000.f) / (float)kND;
    for (int c4 = tid; c4 < kND / 4; c4 += 256) {
      int c = c4 * 4;
      int n = c >> 7, d = c & 127;
      float4 acc = *(const float4*)&emb_b[n * kD + d];
#pragma unroll
      for (int m = 0; m < kM; m++) {
        float xv = xs[n * kM + m];
        float4 w = *(const float4*)&emb_W[((size_t)(n * kM + m)) * kD + d];
        acc.x += xv * w.x; acc.y += xv * w.y; acc.z += xv * w.z; acc.w += xv * w.w;
      }
      float ang0 = (float)b * expf((float)c * c1);
      float ang1 = (float)b * expf((float)(c + 2) * c1);
      acc.x += sinf(ang0); acc.y += cosf(ang0);
      acc.z += sinf(ang1); acc.w += cosf(ang1);
      *(float4*)&hb[(size_t)p * kND + c] = acc;
      union { bf16 h4[4]; uint2 v; } pk;
      pk.h4[0] = __float2bfloat16(acc.x); pk.h4[1] = __float2bfloat16(acc.y);
      pk.h4[2] = __float2bfloat16(acc.z); pk.h4[3] = __float2bfloat16(acc.w);
      *(uint2*)&hbb[(size_t)p * kND + c] = pk.v;
    }
  } else if (bid < OFF_SPK) {
    // ---- spatial Wq -> spW rows [0,128) ----
    int idx = bid - OFF_SPQ;
    int l = idx / 192, rem = idx % 192;
    int hh = rem / 24, n = rem % 24;
    const float* src = sp_Wq + ((((size_t)l * kH + hh) * kN + n)) * (kD * kF);
    bf16* dst = spW + (((size_t)(l * 24 + n)) * 768 + hh * 16) * 128;
    spw_transpose_body(src, dst, (float*)sm, tid);
  } else if (bid < OFF_SPV) {
    // ---- spatial Wk -> spW rows [128,256) ----
    int idx = bid - OFF_SPK;
    int l = idx / 192, rem = idx % 192;
    int hh = rem / 24, n = rem % 24;
    const float* src = sp_Wk + (((size_t)l * kH + hh)) * (kD * kF);
    bf16* dst = spW + (((size_t)(l * 24 + n)) * 768 + 128 + hh * 16) * 128;
    spw_transpose_body(src, dst, (float*)sm, tid);
  } else if (bid < OFF_TMP) {
    // ---- spatial Wv -> spW rows [256,384) ----
    int idx = bid - OFF_SPV;
    int l = idx / 192, rem = idx % 192;
    int hh = rem / 24, n = rem % 24;
    const float* src = sp_Wv + (((size_t)l * kH + hh)) * (kD * kF);
    bf16* dst = spW + (((size_t)(l * 24 + n)) * 768 + 256 + hh * 16) * 128;
    spw_transpose_body(src, dst, (float*)sm, tid);
  } else if (bid < OFF_CVT) {
    // ---- temporal Win -> spW rows [384,768): contiguous cvt per (l,n) ----
    long j8 = ((long)(bid - OFF_TMP) * 256 + tid) * 8;   // over L*24*49152
    long ln = j8 / 49152, rem = j8 % 49152;
    const float* src = &tmp_Win[ln * 49152 + rem];
    float4 v0 = *(const float4*)src, v1 = *(const float4*)(src + 4);
    union { bf16 h[8]; uint4 v; } pk;
    pk.h[0] = __float2bfloat16(v0.x); pk.h[1] = __float2bfloat16(v0.y);
    pk.h[2] = __float2bfloat16(v0.z); pk.h[3] = __float2bfloat16(v0.w);
    pk.h[4] = __float2bfloat16(v1.x); pk.h[5] = __float2bfloat16(v1.y);
    pk.h[6] = __float2bfloat16(v1.z); pk.h[7] = __float2bfloat16(v1.w);
    *(uint4*)&spW[ln * 98304 + 49152 + rem] = pk.v;
  } else if (bid < OFF_SPB) {
    // ---- cvt toWb ----
    int i8 = ((bid - OFF_CVT) * 256 + tid) * 8;
    float4 v0 = *(const float4*)(tmp_Wout + i8);
    float4 v1 = *(const float4*)(tmp_Wout + i8 + 4);
    union { bf16 h[8]; uint4 v; } pk;
    pk.h[0] = __float2bfloat16(v0.x); pk.h[1] = __float2bfloat16(v0.y);
    pk.h[2] = __float2bfloat16(v0.z); pk.h[3] = __float2bfloat16(v0.w);
    pk.h[4] = __float2bfloat16(v1.x); pk.h[5] = __float2bfloat16(v1.y);
    pk.h[6] = __float2bfloat16(v1.z); pk.h[7] = __float2bfloat16(v1.w);
    *(uint4*)(toWb + i8) = pk.v;
  } else if (bid < OFF_W1) {
    // ---- build_spb ----
    int i = (bid - OFF_SPB) * 256 + tid;
    int r = i % 768;
    int n = (i / 768) % 24;
    int l = i / (768 * 24);
    int hh = (r & 127) >> 4, f = r & 15;
    float v;
    if (r < 128)      v = sp_bq[(((size_t)l * kH + hh) * kN + n) * kF + f];
    else if (r < 256) v = sp_bk[((size_t)l * kH + hh) * kF + f];
    else if (r < 384) v = sp_bv[((size_t)l * kH + hh) * kF + f];
    else              v = tmp_bin[((size_t)l * kN + n) * 384 + (r - 384)];
    spbc[i] = v;
  } else if (bid < OFF_W2) {
    // ---- trans_cvt W1: fp32 (kND x kFF) -> bf16 (kFF x kND), per l ----
    int id2 = bid - OFF_W1;
    int bz = id2 / (16 * 48);
    int rem = id2 % (16 * 48);
    trans_cvt_body(ff_W1 + (size_t)bz * kND * kFF, W1t + (size_t)bz * kFF * kND,
                   kND, kFF, rem % 16, rem / 16, (float(*)[65])sm, tid);
  } else if (bid < OFF_FIN) {
    // ---- trans_cvt W2: fp32 (kFF x kND) -> bf16 (kND x kFF), per l ----
    int id2 = bid - OFF_W2;
    int bz = id2 / (48 * 16);
    int rem = id2 % (48 * 16);
    trans_cvt_body(ff_W2 + (size_t)bz * kFF * kND, W2t + (size_t)bz * kND * kFF,
                   kFF, kND, rem % 48, rem / 48, (float(*)[65])sm, tid);
  } else {
    // ---- trans_cvt fin_W: fp32 (kND x kNM) -> bf16 (kNM x kND) ----
    int id2 = bid - OFF_FIN;
    trans_cvt_body(fin_W, finWt, kND, kNM, id2 % 4, id2 / 4, (float(*)[65])sm, tid);
  }
}

// ---------------------------------------------------------------------------
// Spatial attention — float4 LDS traffic throughout.
// ---------------------------------------------------------------------------
__global__ __launch_bounds__(192) void sp_attn_kernel(
    const bf16* __restrict__ qkv, float* __restrict__ out)
{
  int p = blockIdx.x;
  __shared__ float s[24 * 388];
  for (int i = threadIdx.x; i < 2304; i += 192) {
    int n = i / 96, c4 = (i % 96) * 4;
    ushort4 u = *(const ushort4*)((const ushort*)qkv + ((size_t)n * kP + p) * 768 + c4);
    float4 f;
    f.x = __bfloat162float(*(const bf16*)&u.x);
    f.y = __bfloat162float(*(const bf16*)&u.y);
    f.z = __bfloat162float(*(const bf16*)&u.z);
    f.w = __bfloat162float(*(const bf16*)&u.w);
    *(float4*)&s[n * 388 + c4] = f;
  }
  __syncthreads();
  int hh = threadIdx.x / 24, n = threadIdx.x % 24;
  const float4* qr = (const float4*)(s + n * 388 + hh * 16);
  float4 q0 = qr[0], q1 = qr[1], q2 = qr[2], q3 = qr[3];
  float sc[24];
  float mx = -1e30f;
#pragma unroll
  for (int m = 0; m < 24; m++) {
    const float4* kr = (const float4*)(s + m * 388 + 128 + hh * 16);
    float4 k0 = kr[0], k1 = kr[1], k2 = kr[2], k3 = kr[3];
    float d = q0.x * k0.x + q0.y * k0.y + q0.z * k0.z + q0.w * k0.w
            + q1.x * k1.x + q1.y * k1.y + q1.z * k1.z + q1.w * k1.w
            + q2.x * k2.x + q2.y * k2.y + q2.z * k2.z + q2.w * k2.w
            + q3.x * k3.x + q3.y * k3.y + q3.z * k3.z + q3.w * k3.w;
    d *= 0.25f;
    sc[m] = d;
    mx = fmaxf(mx, d);
  }
  float sum = 0.f;
#pragma unroll
  for (int m = 0; m < 24; m++) { float e = __expf(sc[m] - mx); sc[m] = e; sum += e; }
  float inv = 1.f / sum;
  float4 o0 = {0,0,0,0}, o1 = {0,0,0,0}, o2 = {0,0,0,0}, o3 = {0,0,0,0};
#pragma unroll
  for (int m = 0; m < 24; m++) {
    const float4* vr = (const float4*)(s + m * 388 + 256 + hh * 16);
    float4 v0 = vr[0], v1 = vr[1], v2 = vr[2], v3 = vr[3];
    float w = sc[m];
    o0.x += w * v0.x; o0.y += w * v0.y; o0.z += w * v0.z; o0.w += w * v0.w;
    o1.x += w * v1.x; o1.y += w * v1.y; o1.z += w * v1.z; o1.w += w * v1.w;
    o2.x += w * v2.x; o2.y += w * v2.y; o2.z += w * v2.z; o2.w += w * v2.w;
    o3.x += w * v3.x; o3.y += w * v3.y; o3.z += w * v3.z; o3.w += w * v3.w;
  }
  float* orow = out + (size_t)p * kND + n * kD + hh * 16;
  o0.x *= inv; o0.y *= inv; o0.z *= inv; o0.w *= inv;
  o1.x *= inv; o1.y *= inv; o1.z *= inv; o1.w *= inv;
  o2.x *= inv; o2.y *= inv; o2.z *= inv; o2.w *= inv;
  o3.x *= inv; o3.y *= inv; o3.z *= inv; o3.w *= inv;
  *(float4*)(orow)      = o0;
  *(float4*)(orow + 4)  = o1;
  *(float4*)(orow + 8)  = o2;
  *(float4*)(orow + 12) = o3;
}

// ---------------------------------------------------------------------------
// Temporal attention via MFMA, one block per (b,n,h), 128 threads (2 waves).
// Ps ALIASES the dead Qs/Ks region (r5/r6-verified numerically): LDS 39.2 KB.
// ---------------------------------------------------------------------------
__global__ __launch_bounds__(128) void t_attn_mfma(
    const bf16* __restrict__ qkv, bf16* __restrict__ ot)
{
  int g = blockIdx.x;
  int hh = g & 7, n = (g >> 3) % 24, b = g / 192;
  __shared__ __align__(16) char smem[39168];
  ushort (*Qs)[40]  = (ushort(*)[40])(smem);            // [0,10240)
  ushort (*Ks)[40]  = (ushort(*)[40])(smem + 10240);    // [10240,20480)
  ushort (*Ps)[136] = (ushort(*)[136])(smem);           // [0,34816) aliases Qs/Ks
  ushort (*Vt)[136] = (ushort(*)[136])(smem + 34816);   // [34816,39168)

  for (int idx = threadIdx.x; idx < 256; idx += 128) {
    int t = idx >> 1, e8 = (idx & 1) * 8;
    const ushort* src = (const ushort*)qkv +
        ((size_t)n * kP + (size_t)t * kB + b) * 768 + 384 + hh * 16 + e8;
    uint4 q = *(const uint4*)(src);
    uint4 k = *(const uint4*)(src + 128);
    uint4 v = *(const uint4*)(src + 256);
    *(uint4*)&Qs[t][e8] = q;
    *(uint4*)&Ks[t][e8] = k;
    *(uint4*)&Qs[t][16 + e8] = make_uint4(0, 0, 0, 0);
    *(uint4*)&Ks[t][16 + e8] = make_uint4(0, 0, 0, 0);
    const ushort* vp = (const ushort*)&v;
#pragma unroll
    for (int j = 0; j < 8; j++) Vt[e8 + j][t] = vp[j];
  }
  __syncthreads();

  int lane = threadIdx.x & 63, w = threadIdx.x >> 6;
  int c = lane & 15, quad = lane >> 4;

  // S = Q K^T (Qs/Ks fully consumed into registers here)
  bf16x8 aq[4];
#pragma unroll
  for (int mt = 0; mt < 4; mt++)
    aq[mt] = *(const bf16x8*)&Qs[w * 64 + mt * 16 + c][quad * 8];
  f32x4 acc[4][8];
#pragma unroll
  for (int nt = 0; nt < 8; nt++) {
    bf16x8 bk = *(const bf16x8*)&Ks[nt * 16 + c][quad * 8];
#pragma unroll
    for (int mt = 0; mt < 4; mt++) {
      f32x4 z = {0.f, 0.f, 0.f, 0.f};
      acc[mt][nt] = __builtin_amdgcn_mfma_f32_16x16x32_bf16(aq[mt], bk, z, 0, 0, 0);
    }
  }
  __syncthreads();   // Qs/Ks dead -> Ps may overwrite

  // softmax per row; rows t = w*64 + mt*16 + quad*4 + r, cols s = nt*16 + c
  f32x4 invv[4];
#pragma unroll
  for (int mt = 0; mt < 4; mt++) {
    int tbase = w * 64 + mt * 16 + quad * 4;
    f32x4 rm = {-1e30f, -1e30f, -1e30f, -1e30f};
#pragma unroll
    for (int nt = 0; nt < 8; nt++) {
      int s = nt * 16 + c;
#pragma unroll
      for (int r = 0; r < 4; r++) {
        float x = acc[mt][nt][r] * 0.25f + ((s < tbase + r) ? 1.f : 0.f);
        acc[mt][nt][r] = x;
        rm[r] = fmaxf(rm[r], x);
      }
    }
#pragma unroll
    for (int off = 1; off < 16; off <<= 1)
#pragma unroll
      for (int r = 0; r < 4; r++) rm[r] = fmaxf(rm[r], __shfl_xor(rm[r], off, 64));
    f32x4 rs = {0.f, 0.f, 0.f, 0.f};
#pragma unroll
    for (int nt = 0; nt < 8; nt++)
#pragma unroll
      for (int r = 0; r < 4; r++) {
        float pp = __expf(acc[mt][nt][r] - rm[r]);
        acc[mt][nt][r] = pp;
        rs[r] += pp;
      }
#pragma unroll
    for (int off = 1; off < 16; off <<= 1)
#pragma unroll
      for (int r = 0; r < 4; r++) rs[r] += __shfl_xor(rs[r], off, 64);
#pragma unroll
    for (int r = 0; r < 4; r++) invv[mt][r] = 1.f / rs[r];
#pragma unroll
    for (int nt = 0; nt < 8; nt++)
#pragma unroll
      for (int r = 0; r < 4; r++) {
        bf16 pb = __float2bfloat16(acc[mt][nt][r]);
        Ps[tbase + r][nt * 16 + c] = *(ushort*)&pb;
      }
  }

  // O = P V (in-wave Ps reuse only)
  f32x4 o[4] = {};
#pragma unroll
  for (int ks = 0; ks < 128; ks += 32) {
    bf16x8 bv = *(const bf16x8*)&Vt[c][ks + quad * 8];
#pragma unroll
    for (int mt = 0; mt < 4; mt++) {
      bf16x8 ap = *(const bf16x8*)&Ps[w * 64 + mt * 16 + c][ks + quad * 8];
      o[mt] = __builtin_amdgcn_mfma_f32_16x16x32_bf16(ap, bv, o[mt], 0, 0, 0);
    }
  }

#pragma unroll
  for (int mt = 0; mt < 4; mt++) {
#pragma unroll
    for (int r = 0; r < 4; r++) {
      int t = w * 64 + mt * 16 + quad * 4 + r;
      float val = o[mt][r] * invv[mt][r];
      ot[((size_t)n * kP + (size_t)t * kB + b) * 128 + hh * 16 + c] = __float2bfloat16(val);
    }
  }
}

// ---------------------------------------------------------------------------
// Fused: a2 = LN(sp+h) + LN(tp+h); float4 traffic; writes a2 fp32 + bf16
// ---------------------------------------------------------------------------
__global__ __launch_bounds__(256) void fuse_a2_kernel(
    const float* __restrict__ sp, const float* __restrict__ tp,
    const float* __restrict__ h, const float* __restrict__ g,
    const float* __restrict__ be, float* __restrict__ a2, bf16* __restrict__ a2b)
{
  int row = blockIdx.x;
  const float4* s1p = (const float4*)(sp + (size_t)row * kND);
  const float4* s2p = (const float4*)(tp + (size_t)row * kND);
  const float4* hp  = (const float4*)(h  + (size_t)row * kND);
  float4 x1[3], x2[3];
  float sum1 = 0.f, sum2 = 0.f;
#pragma unroll
  for (int i = 0; i < 3; i++) {
    int c = threadIdx.x + 256 * i;
    float4 hv = hp[c], a = s1p[c], bb = s2p[c];
    a.x += hv.x; a.y += hv.y; a.z += hv.z; a.w += hv.w;
    bb.x += hv.x; bb.y += hv.y; bb.z += hv.z; bb.w += hv.w;
    x1[i] = a; x2[i] = bb;
    sum1 += a.x + a.y + a.z + a.w;
    sum2 += bb.x + bb.y + bb.z + bb.w;
  }
  __shared__ float red1[4], red2[4];
#pragma unroll
  for (int o = 32; o > 0; o >>= 1) { sum1 += __shfl_down(sum1, o, 64); sum2 += __shfl_down(sum2, o, 64); }
  int wid = threadIdx.x >> 6;
  if ((threadIdx.x & 63) == 0) { red1[wid] = sum1; red2[wid] = sum2; }
  __syncthreads();
  float mean1 = (red1[0] + red1[1] + red1[2] + red1[3]) * (1.f / kND);
  float mean2 = (red2[0] + red2[1] + red2[2] + red2[3]) * (1.f / kND);
  __syncthreads();
  float v1 = 0.f, v2 = 0.f;
#pragma unroll
  for (int i = 0; i < 3; i++) {
    float4 a = x1[i], bb = x2[i];
    v1 += (a.x - mean1) * (a.x - mean1) + (a.y - mean1) * (a.y - mean1)
        + (a.z - mean1) * (a.z - mean1) + (a.w - mean1) * (a.w - mean1);
    v2 += (bb.x - mean2) * (bb.x - mean2) + (bb.y - mean2) * (bb.y - mean2)
        + (bb.z - mean2) * (bb.z - mean2) + (bb.w - mean2) * (bb.w - mean2);
  }
#pragma unroll
  for (int o = 32; o > 0; o >>= 1) { v1 += __shfl_down(v1, o, 64); v2 += __shfl_down(v2, o, 64); }
  if ((threadIdx.x & 63) == 0) { red1[wid] = v1; red2[wid] = v2; }
  __syncthreads();
  float r1 = rsqrtf((red1[0] + red1[1] + red1[2] + red1[3]) * (1.f / kND) + 1e-5f);
  float r2 = rsqrtf((red2[0] + red2[1] + red2[2] + red2[3]) * (1.f / kND) + 1e-5f);
  const float4* g4 = (const float4*)g;
  const float4* b4 = (const float4*)be;
#pragma unroll
  for (int i = 0; i < 3; i++) {
    int c = threadIdx.x + 256 * i;
    float4 gc = g4[c], bc = b4[c];
    float4 a = x1[i], bb = x2[i], o;
    o.x = (a.x - mean1) * r1 * gc.x + bc.x + (bb.x - mean2) * r2 * gc.x + bc.x;
    o.y = (a.y - mean1) * r1 * gc.y + bc.y + (bb.y - mean2) * r2 * gc.y + bc.y;
    o.z = (a.z - mean1) * r1 * gc.z + bc.z + (bb.z - mean2) * r2 * gc.z + bc.z;
    o.w = (a.w - mean1) * r1 * gc.w + bc.w + (bb.w - mean2) * r2 * gc.w + bc.w;
    *(float4*)(a2 + (size_t)row * kND + c * 4) = o;
    union { bf16 h4[4]; uint2 v; } pk;
    pk.h4[0] = __float2bfloat16(o.x); pk.h4[1] = __float2bfloat16(o.y);
    pk.h4[2] = __float2bfloat16(o.z); pk.h4[3] = __float2bfloat16(o.w);
    *(uint2*)(a2b + (size_t)row * kND + c * 4) = pk.v;
  }
}

// out = LN(a + b); float4 traffic; writes fp32 + bf16
__global__ __launch_bounds__(256) void add_ln_dual_kernel(
    const float* __restrict__ a, const float* __restrict__ b,
    const float* __restrict__ g, const float* __restrict__ be,
    float* __restrict__ out, bf16* __restrict__ outb)
{
  int row = blockIdx.x;
  const float4* ar = (const float4*)(a + (size_t)row * kND);
  const float4* br = (const float4*)(b + (size_t)row * kND);
  float4 v[3];
  float s = 0.f;
#pragma unroll
  for (int i = 0; i < 3; i++) {
    int c = threadIdx.x + 256 * i;
    float4 x = ar[c], y = br[c];
    x.x += y.x; x.y += y.y; x.z += y.z; x.w += y.w;
    v[i] = x;
    s += x.x + x.y + x.z + x.w;
  }
  __shared__ float red[4];
#pragma unroll
  for (int o = 32; o > 0; o >>= 1) s += __shfl_down(s, o, 64);
  int wid = threadIdx.x >> 6;
  if ((threadIdx.x & 63) == 0) red[wid] = s;
  __syncthreads();
  float mean = (red[0] + red[1] + red[2] + red[3]) * (1.f / kND);
  __syncthreads();
  float vs = 0.f;
#pragma unroll
  for (int i = 0; i < 3; i++) {
    float4 x = v[i];
    vs += (x.x - mean) * (x.x - mean) + (x.y - mean) * (x.y - mean)
        + (x.z - mean) * (x.z - mean) + (x.w - mean) * (x.w - mean);
  }
#pragma unroll
  for (int o = 32; o > 0; o >>= 1) vs += __shfl_down(vs, o, 64);
  if ((threadIdx.x & 63) == 0) red[wid] = vs;
  __syncthreads();
  float rstd = rsqrtf((red[0] + red[1] + red[2] + red[3]) * (1.f / kND) + 1e-5f);
  const float4* g4 = (const float4*)g;
  const float4* b4 = (const float4*)be;
#pragma unroll
  for (int i = 0; i < 3; i++) {
    int c = threadIdx.x + 256 * i;
    float4 gc = g4[c], bc = b4[c], x = v[i], o;
    o.x = (x.x - mean) * rstd * gc.x + bc.x;
    o.y = (x.y - mean) * rstd * gc.y + bc.y;
    o.z = (x.z - mean) * rstd * gc.z + bc.z;
    o.w = (x.w - mean) * rstd * gc.w + bc.w;
    *(float4*)(out + (size_t)row * kND + c * 4) = o;
    union { bf16 h4[4]; uint2 v2; } pk;
    pk.h4[0] = __float2bfloat16(o.x); pk.h4[1] = __float2bfloat16(o.y);
    pk.h4[2] = __float2bfloat16(o.z); pk.h4[3] = __float2bfloat16(o.w);
    *(uint2*)(outb + (size_t)row * kND + c * 4) = pk.v2;
  }
}

// FF1 split-K reduce: f1b[i] = bf16(p0+p1+p2 + bias[col])
__global__ __launch_bounds__(256) void ff1_reduce_kernel(
    const float* __restrict__ part, const float* __restrict__ bias,
    bf16* __restrict__ out)
{
  int i4 = (blockIdx.x * 256 + threadIdx.x) * 4;   // grid covers kP*kFF/4
  const size_t S = (size_t)kP * kFF;
  float4 p0 = *(const float4*)(part + i4);
  float4 p1 = *(const float4*)(part + S + i4);
  float4 p2 = *(const float4*)(part + 2 * S + i4);
  int col = i4 & (kFF - 1);
  float4 bb = *(const float4*)(bias + col);
  union { bf16 h4[4]; uint2 v; } pk;
  pk.h4[0] = __float2bfloat16(p0.x + p1.x + p2.x + bb.x);
  pk.h4[1] = __float2bfloat16(p0.y + p1.y + p2.y + bb.y);
  pk.h4[2] = __float2bfloat16(p0.z + p1.z + p2.z + bb.z);
  pk.h4[3] = __float2bfloat16(p0.w + p1.w + p2.w + bb.w);
  *(uint2*)(out + i4) = pk.v;
}

// Final: out[b,t,c] = sum_z part[z][(t*B+b)*216+c] + fin_b[c] + inputs[b,t,c]
__global__ __launch_bounds__(256) void final_reduce_add_kernel(
    const float* __restrict__ part, const float* __restrict__ fin_b,
    const float* __restrict__ inp, float* __restrict__ out)
{
  int i = blockIdx.x * 256 + threadIdx.x;
  if (i >= kB * kT * kNM) return;
  int c = i % kNM;
  int rem = i / kNM;
  int t = rem % kT, b = rem / kT;
  size_t pi = (size_t)(t * kB + b) * kNM + c;
  const size_t S = (size_t)kP * kNM;
  float v = fin_b[c] + inp[i];
#pragma unroll
  for (int z = 0; z < 8; z++) v += part[z * S + pi];
  out[i] = v;
}

// ---------------------------------------------------------------------------
extern "C" void kernel_launch(void* const* d_in, const int* in_sizes, int n_in,
                              void* d_out, int out_size, void* d_ws, size_t ws_size,
                              hipStream_t stream)
{
  const float* inputs   = (const float*)d_in[0];
  const float* emb_W    = (const float*)d_in[1];
  const float* emb_b    = (const float*)d_in[2];
  const float* sp_Wq    = (const float*)d_in[3];
  const float* sp_bq    = (const float*)d_in[4];
  const float* sp_Wk    = (const float*)d_in[5];
  const float* sp_bk    = (const float*)d_in[6];
  const float* sp_Wv    = (const float*)d_in[7];
  const float* sp_bv    = (const float*)d_in[8];
  const float* tmp_Win  = (const float*)d_in[9];
  const float* tmp_bin  = (const float*)d_in[10];
  const float* tmp_Wout = (const float*)d_in[11];
  const float* tmp_bout = (const float*)d_in[12];
  const float* ff_W1    = (const float*)d_in[13];
  const float* ff_b1    = (const float*)d_in[14];
  const float* ff_W2    = (const float*)d_in[15];
  const float* ff_b2    = (const float*)d_in[16];
  const float* ln_g     = (const float*)d_in[17];
  const float* ln_b     = (const float*)d_in[18];
  const float* fin_W    = (const float*)d_in[19];
  const float* fin_b    = (const float*)d_in[20];
  float* out = (float*)d_out;

  // ---- workspace layout ----
  char* wp = (char*)d_ws;
  size_t off = 0;
  auto alloc = [&](size_t bytes) { void* p = wp + off; off += (bytes + 255) & ~(size_t)255; return p; };
  bf16* spW   = (bf16*)alloc((size_t)kL * 24 * 768 * 128 * 2);  // fused qkv weights
  bf16* toWb  = (bf16*)alloc((size_t)kL * 24 * 128 * 128 * 2);
  bf16* W1t   = (bf16*)alloc((size_t)kL * kFF * kND * 2);
  bf16* W2t   = (bf16*)alloc((size_t)kL * kND * kFF * 2);
  bf16* finWt = (bf16*)alloc((size_t)kNM * kND * 2);
  float* spbc = (float*)alloc((size_t)kL * 24 * 768 * 4);
  float* hb   = (float*)alloc((size_t)kP * kND * 4);
  bf16*  hbb  = (bf16*) alloc((size_t)kP * kND * 2);
  bf16*  qkvb = (bf16*) alloc((size_t)24 * kP * 768 * 2);   // fused spatial+temporal qkv
  float* sp   = (float*)alloc((size_t)kP * kND * 4);        // spatial out; FF1 partials
  float* tp   = (float*)alloc((size_t)kP * kND * 4);        // temporal out; FF2 out; final partials
  float* a2   = (float*)alloc((size_t)kP * kND * 4);
  bf16*  a2b  = (bf16*) alloc((size_t)kP * kND * 2);
  bf16*  f1b  = (bf16*) alloc((size_t)kP * kFF * 2);
  bf16*  otb  = (bf16*) alloc((size_t)24 * kP * 128 * 2);
  float* ffpart  = sp;   // 3 * kP*kFF fp32 = 12 MB (sp dead during FF)
  float* finpart = tp;   // 8 * kP*kNM fp32 = 6.9 MB (tp dead after loop)

  // ---- all weight prep + embedding: ONE dispatch ----
  prep_kernel<<<NB_PREP, 256, 0, stream>>>(
      sp_Wq, sp_Wk, sp_Wv, tmp_Win, spW,
      tmp_Wout, toWb,
      sp_bq, sp_bk, sp_bv, tmp_bin, spbc,
      ff_W1, W1t, ff_W2, W2t, fin_W, finWt,
      inputs, emb_W, emb_b, hb, hbb);

  for (int l = 0; l < kL; l++) {
    const float* lg = ln_g + (size_t)l * kND;
    const float* lb = ln_b + (size_t)l * kND;

    // fused spatial+temporal qkv: groups n; C = qkvb (n, p, 768) bf16
    mfma_gemm<128, 128, true><<<dim3(6, 8, 24), 256, 0, stream>>>(
        hbb, spW + (size_t)l * 24 * 768 * 128, spbc + (size_t)l * 24 * 768, qkvb,
        kP, 768, 128, /*ldB*/128, /*sAi*/kND, /*sCi*/768,
        /*offAg*/128, /*offBg*/768 * 128, /*offCg*/(long)kP * 768, /*sBg*/768);

    sp_attn_kernel<<<kP, 192, 0, stream>>>(qkvb, sp);
    t_attn_mfma<<<kB * 24 * 8, 128, 0, stream>>>(qkvb, otb);

    // temporal out-proj: 64x64 tiles -> 768 blocks
    mfma_gemm<64, 64, false><<<dim3(2, 16, 24), 256, 0, stream>>>(
        otb, toWb + (size_t)l * 24 * 128 * 128, tmp_bout + (size_t)l * 24 * 128, tp,
        kP, 128, 128, /*ldB*/128, /*sAi*/128, /*sCi*/kND,
        /*offAg*/(long)kP * 128, /*offBg*/128 * 128, /*offCg*/128, /*sBg*/128);

    fuse_a2_kernel<<<kP, 256, 0, stream>>>(sp, tp, hb, lg, lb, a2, a2b);

    // FF1 split-K=3: 768 blocks, K-chunk 1024, fp32 partials -> ffpart
    mfma_gemm<64, 64, false><<<dim3(kFF / 64, kP / 64, 3), 256, 0, stream>>>(
        a2b, W1t + (size_t)l * kFF * kND, nullptr, ffpart,
        kP, kFF, /*K*/kND / 3, /*ldB*/kND, /*sAi*/kND, /*sCi*/kFF,
        /*offAg*/kND / 3, /*offBg*/kND / 3, /*offCg*/(long)kP * kFF, /*sBg*/0);
    ff1_reduce_kernel<<<(kP * kFF / 4) / 256, 256, 0, stream>>>(
        ffpart, ff_b1 + (size_t)l * kFF, f1b);

    // FF2: 64x64 tiles -> 768 blocks
    mfma_gemm<64, 64, false><<<dim3(kND / 64, kP / 64, 1), 256, 0, stream>>>(
        f1b, W2t + (size_t)l * kND * kFF, ff_b2 + (size_t)l * kND, tp,
        kP, kND, kFF, /*ldB*/kFF, /*sAi*/kFF, /*sCi*/kND, 0, 0, 0, 0);

    add_ln_dual_kernel<<<kP, 256, 0, stream>>>(tp, a2, lg, lb, hb, hbb);
  }

  // final projection: split-K=8 (K-chunk 384) -> 512 blocks; fused reduce+residual
  mfma_gemm<64, 64, false><<<dim3((kNM + 63) / 64, kP / 64, 8), 256, 0, stream>>>(
      hbb, finWt, nullptr, finpart,
      kP, kNM, /*K*/kND / 8, /*ldB*/kND, /*sAi*/kND, /*sCi*/kNM,
      /*offAg*/kND / 8, /*offBg*/kND / 8, /*offCg*/(long)kP * kNM, /*sBg*/0);
  final_reduce_add_kernel<<<(kB * kT * kNM + 255) / 256, 256, 0, stream>>>(
      finpart, fin_b, inputs, out);
}

// Round 8
// 723.502 us; speedup vs baseline: 1.2223x; 1.0546x over previous
//
#include <hip/hip_runtime.h>
#include <hip/hip_bf16.h>
#include <math.h>

// Problem constants
constexpr int kB = 8, kT = 128, kN = 24, kD = 128, kM = 9, kH = 8, kL = 4, kFF = 1024;
constexpr int kF = 16;          // D/H
constexpr int kHD = 16;         // D/H
constexpr int kND = kN * kD;    // 3072
constexpr int kNM = kN * kM;    // 216
constexpr int kP = kB * kT;     // 1024 tokens, p = t*B + b

using bf16x8 = __attribute__((ext_vector_type(8))) short;
using f32x4  = __attribute__((ext_vector_type(4))) float;
typedef __hip_bfloat16 bf16;

__device__ __forceinline__ void load_lds16(const void* g, void* l) {
  __builtin_amdgcn_global_load_lds(
      (const __attribute__((address_space(1))) void*)g,
      (__attribute__((address_space(3))) void*)l, 16, 0, 0);
}

// ---------------------------------------------------------------------------
// MFMA bf16 GEMM, BK=64, XOR-swizzled LDS (conflict-free b128 fragment reads,
// wave-contiguous global_load_lds staging).
// ---------------------------------------------------------------------------
template<int BM, int BN, bool OUTBF>
__global__ __launch_bounds__(256) void mfma_gemm(
    const bf16* __restrict__ A, const bf16* __restrict__ Bm,
    const float* __restrict__ bias, void* __restrict__ Cv,
    int M, int Nc, int K, int ldB, int sAi, int sCi,
    long offAg, long offBg, long offCg, int sBg)
{
  constexpr int WM = BM / 2, WN = BN / 2;
  constexpr int MT = WM / 16, NT = WN / 16;
  constexpr int ASLOTS = BM * 8;   // 16-B slots (BM rows x 128 B per k-chunk)
  constexpr int BSLOTS = BN * 8;
  constexpr int CSTR = BN + 4;     // repack stride (floats)
  __shared__ __align__(16) char smem[(BM + BN) * 64 * 2];
  bf16* As = (bf16*)smem;
  bf16* Bs = (bf16*)(smem + BM * 64 * 2);
  float* Cs = (float*)smem;        // epilogue repack area

  int g = blockIdx.z;
  A  += offAg * g;
  Bm += offBg * g;
  long cbase = offCg * (long)g;
  int bOff = sBg * g;

  int m0 = blockIdx.y * BM, n0 = blockIdx.x * BN;
  int tid = threadIdx.x, lane = tid & 63, wave = tid >> 6;
  int wm = wave >> 1, wn = wave & 1;
  int fr = lane & 15, fq = lane >> 4;

  f32x4 acc[MT][NT] = {};

  for (int kk = 0; kk < K; kk += 64) {
#pragma unroll
    for (int s = tid; s < ASLOTS; s += 256) {
      int m = s >> 3, kq = (s & 7) ^ (m & 7);     // XOR swizzle
      load_lds16(A + (size_t)(m0 + m) * sAi + (kk + kq * 8), &As[s * 8]);
    }
#pragma unroll
    for (int s = tid; s < BSLOTS; s += 256) {
      int n = s >> 3, kq = (s & 7) ^ (n & 7);
      int nr = n0 + n; if (nr > Nc - 1) nr = Nc - 1;   // clamp ragged N
      load_lds16(Bm + (size_t)nr * ldB + (kk + kq * 8), &Bs[s * 8]);
    }
    __syncthreads();
#pragma unroll
    for (int ks = 0; ks < 2; ks++) {
      bf16x8 af[MT], bfr[NT];
#pragma unroll
      for (int i = 0; i < MT; i++) {
        int row = wm * WM + i * 16 + fr;
        af[i] = *(const bf16x8*)&As[row * 64 + (((ks * 4 + fq) ^ (row & 7)) * 8)];
      }
#pragma unroll
      for (int j = 0; j < NT; j++) {
        int row = wn * WN + j * 16 + fr;
        bfr[j] = *(const bf16x8*)&Bs[row * 64 + (((ks * 4 + fq) ^ (row & 7)) * 8)];
      }
#pragma unroll
      for (int i = 0; i < MT; i++)
#pragma unroll
        for (int j = 0; j < NT; j++)
          acc[i][j] = __builtin_amdgcn_mfma_f32_16x16x32_bf16(af[i], bfr[j], acc[i][j], 0, 0, 0);
    }
    __syncthreads();
  }

  // ---- epilogue: per m-tile round, repack 32 rows x BN through LDS ----
  constexpr int NCHUNK = BN / 16;
  int tcol = tid & (NCHUNK - 1);
  int trow = tid / NCHUNK;          // row within the 32-row round
  int colbase = n0 + tcol * 16;
  float vb[16];
  if (trow < 32) {
#pragma unroll
    for (int jj = 0; jj < 16; jj++)
      vb[jj] = bias ? bias[bOff + colbase + jj] : 0.f;
  }
#pragma unroll
  for (int i = 0; i < MT; i++) {
    __syncthreads();
#pragma unroll
    for (int j = 0; j < NT; j++)
#pragma unroll
      for (int r = 0; r < 4; r++)
        Cs[(wm * 16 + fq * 4 + r) * CSTR + wn * WN + j * 16 + fr] = acc[i][j][r];
    __syncthreads();
    if (trow < 32) {
      int row = m0 + (trow >> 4) * WM + i * 16 + (trow & 15);
      float vals[16];
#pragma unroll
      for (int jj = 0; jj < 4; jj++)
        *(float4*)&vals[jj * 4] = *(const float4*)&Cs[trow * CSTR + tcol * 16 + jj * 4];
#pragma unroll
      for (int jj = 0; jj < 16; jj++) vals[jj] += vb[jj];
      if (OUTBF) {
        bf16* cp = (bf16*)Cv + cbase + (size_t)row * sCi + colbase;
        union { bf16 h[8]; uint4 v; } pk;
#pragma unroll
        for (int half = 0; half < 2; half++) {
          if (colbase + half * 8 + 8 <= Nc) {
#pragma unroll
            for (int jj = 0; jj < 8; jj++) pk.h[jj] = __float2bfloat16(vals[half * 8 + jj]);
            *(uint4*)(cp + half * 8) = pk.v;
          }
        }
      } else {
        float* cp = (float*)Cv + cbase + (size_t)row * sCi + colbase;
#pragma unroll
        for (int jj = 0; jj < 4; jj++)
          if (colbase + jj * 4 + 4 <= Nc) *(float4*)(cp + jj * 4) = *(float4*)&vals[jj * 4];
      }
    }
  }
}

// ---------------------------------------------------------------------------
// Mega prep kernel: all weight prep + embedding in ONE dispatch.
// ---------------------------------------------------------------------------
constexpr int NB_EMB = kP;                                     // 1024
constexpr int NB_SPQ = kL * kH * kN;                           // 768
constexpr int NB_SPK = kL * kH * kN;                           // 768
constexpr int NB_SPV = kL * kH * kN;                           // 768
constexpr int NB_TMP = (kL * kN * 384 * kD / 8) / 256;         // 2304
constexpr int NB_CVT = (kL * 24 * 128 * 128 / 8) / 256;        // 768
constexpr int NB_SPB = (kL * 24 * 768) / 256;                  // 288
constexpr int NB_W1  = (kFF / 64) * (kND / 64) * kL;           // 3072
constexpr int NB_W2  = (kND / 64) * (kFF / 64) * kL;           // 3072
constexpr int NB_FIN = ((kNM + 63) / 64) * (kND / 64);         // 192
constexpr int OFF_SPQ = NB_EMB;
constexpr int OFF_SPK = OFF_SPQ + NB_SPQ;
constexpr int OFF_SPV = OFF_SPK + NB_SPK;
constexpr int OFF_TMP = OFF_SPV + NB_SPV;
constexpr int OFF_CVT = OFF_TMP + NB_TMP;
constexpr int OFF_SPB = OFF_CVT + NB_CVT;
constexpr int OFF_W1  = OFF_SPB + NB_SPB;
constexpr int OFF_W2  = OFF_W1 + NB_W1;
constexpr int OFF_FIN = OFF_W2 + NB_W2;
constexpr int NB_PREP = OFF_FIN + NB_FIN;                      // 13024

__device__ __forceinline__ void trans_cvt_body(
    const float* __restrict__ in, bf16* __restrict__ out,
    int R, int C, int bx, int by, float (*t)[65], int tid)
{
  int c0 = bx * 64, r0 = by * 64;
  for (int s = tid; s < 1024; s += 256) {
    int rr = s >> 4, c4 = (s & 15) * 4;
    int r = r0 + rr, c = c0 + c4;
    float4 v;
    if (c + 4 <= C) v = *(const float4*)&in[(size_t)r * C + c];
    else {
      float tmp[4];
#pragma unroll
      for (int j = 0; j < 4; j++) tmp[j] = (c + j < C) ? in[(size_t)r * C + c + j] : 0.f;
      v = *(float4*)tmp;
    }
    *(float4*)&t[rr][c4] = v;
  }
  __syncthreads();
  for (int s = tid; s < 512; s += 256) {
    int cc = s >> 3, r8 = (s & 7) * 8;
    int c = c0 + cc;
    if (c < C) {
      union { bf16 h[8]; uint4 v; } pk;
#pragma unroll
      for (int j = 0; j < 8; j++) pk.h[j] = __float2bfloat16(t[r8 + j][cc]);
      *(uint4*)&out[(size_t)c * R + r0 + r8] = pk.v;
    }
  }
}

// 128x16 fp32 panel (d-major, f innermost) -> 16 rows x 128 bf16 (d innermost).
__device__ __forceinline__ void spw_transpose_body(
    const float* __restrict__ src, bf16* __restrict__ dst, float* ts, int tid)
{
  for (int s = tid; s < 512; s += 256) {
    float4 v = ((const float4*)src)[s];
    int d = s >> 2, f4 = (s & 3) * 4;
    ts[(f4 + 0) * 132 + d] = v.x;
    ts[(f4 + 1) * 132 + d] = v.y;
    ts[(f4 + 2) * 132 + d] = v.z;
    ts[(f4 + 3) * 132 + d] = v.w;
  }
  __syncthreads();
  int f = tid >> 4, d8 = (tid & 15) * 8;
  float4 a = *(const float4*)&ts[f * 132 + d8];
  float4 b = *(const float4*)&ts[f * 132 + d8 + 4];
  union { bf16 h[8]; uint4 v; } pk;
  pk.h[0] = __float2bfloat16(a.x); pk.h[1] = __float2bfloat16(a.y);
  pk.h[2] = __float2bfloat16(a.z); pk.h[3] = __float2bfloat16(a.w);
  pk.h[4] = __float2bfloat16(b.x); pk.h[5] = __float2bfloat16(b.y);
  pk.h[6] = __float2bfloat16(b.z); pk.h[7] = __float2bfloat16(b.w);
  *(uint4*)&dst[(size_t)f * 128 + d8] = pk.v;
}

__global__ __launch_bounds__(256) void prep_kernel(
    const float* __restrict__ sp_Wq, const float* __restrict__ sp_Wk,
    const float* __restrict__ sp_Wv, const float* __restrict__ tmp_Win,
    bf16* __restrict__ spW,
    const float* __restrict__ tmp_Wout, bf16* __restrict__ toWb,
    const float* __restrict__ sp_bq, const float* __restrict__ sp_bk,
    const float* __restrict__ sp_bv, const float* __restrict__ tmp_bin,
    float* __restrict__ spbc,
    const float* __restrict__ ff_W1, bf16* __restrict__ W1t,
    const float* __restrict__ ff_W2, bf16* __restrict__ W2t,
    const float* __restrict__ fin_W, bf16* __restrict__ finWt,
    const float* __restrict__ inp, const float* __restrict__ emb_W,
    const float* __restrict__ emb_b, float* __restrict__ hb,
    bf16* __restrict__ hbb)
{
  __shared__ __align__(16) char sm[64 * 65 * 4];
  int bid = blockIdx.x, tid = threadIdx.x;

  if (bid < OFF_SPQ) {
    // ---- embedding (latency/transcendental-bound: schedule first) ----
    int p = bid;
    int t = p / kB, b = p % kB;
    float* xs = (float*)sm;
    if (tid < kNM)
      xs[tid] = inp[((size_t)b * kT + t) * kNM + tid];
    __syncthreads();
    const float c1 = -logf(10000.f) / (float)kND;
    for (int c4 = tid; c4 < kND / 4; c4 += 256) {
      int c = c4 * 4;
      int n = c >> 7, d = c & 127;
      float4 acc = *(const float4*)&emb_b[n * kD + d];
#pragma unroll
      for (int m = 0; m < kM; m++) {
        float xv = xs[n * kM + m];
        float4 w = *(const float4*)&emb_W[((size_t)(n * kM + m)) * kD + d];
        acc.x += xv * w.x; acc.y += xv * w.y; acc.z += xv * w.z; acc.w += xv * w.w;
      }
      float ang0 = (float)b * expf((float)c * c1);
      float ang1 = (float)b * expf((float)(c + 2) * c1);
      acc.x += sinf(ang0); acc.y += cosf(ang0);
      acc.z += sinf(ang1); acc.w += cosf(ang1);
      *(float4*)&hb[(size_t)p * kND + c] = acc;
      union { bf16 h4[4]; uint2 v; } pk;
      pk.h4[0] = __float2bfloat16(acc.x); pk.h4[1] = __float2bfloat16(acc.y);
      pk.h4[2] = __float2bfloat16(acc.z); pk.h4[3] = __float2bfloat16(acc.w);
      *(uint2*)&hbb[(size_t)p * kND + c] = pk.v;
    }
  } else if (bid < OFF_SPK) {
    // ---- spatial Wq -> spW rows [0,128) ----
    int idx = bid - OFF_SPQ;
    int l = idx / 192, rem = idx % 192;
    int hh = rem / 24, n = rem % 24;
    const float* src = sp_Wq + ((((size_t)l * kH + hh) * kN + n)) * (kD * kF);
    bf16* dst = spW + (((size_t)(l * 24 + n)) * 768 + hh * 16) * 128;
    spw_transpose_body(src, dst, (float*)sm, tid);
  } else if (bid < OFF_SPV) {
    // ---- spatial Wk -> spW rows [128,256) ----
    int idx = bid - OFF_SPK;
    int l = idx / 192, rem = idx % 192;
    int hh = rem / 24, n = rem % 24;
    const float* src = sp_Wk + (((size_t)l * kH + hh)) * (kD * kF);
    bf16* dst = spW + (((size_t)(l * 24 + n)) * 768 + 128 + hh * 16) * 128;
    spw_transpose_body(src, dst, (float*)sm, tid);
  } else if (bid < OFF_TMP) {
    // ---- spatial Wv -> spW rows [256,384) ----
    int idx = bid - OFF_SPV;
    int l = idx / 192, rem = idx % 192;
    int hh = rem / 24, n = rem % 24;
    const float* src = sp_Wv + (((size_t)l * kH + hh)) * (kD * kF);
    bf16* dst = spW + (((size_t)(l * 24 + n)) * 768 + 256 + hh * 16) * 128;
    spw_transpose_body(src, dst, (float*)sm, tid);
  } else if (bid < OFF_CVT) {
    // ---- temporal Win -> spW rows [384,768): contiguous cvt per (l,n) ----
    long j8 = ((long)(bid - OFF_TMP) * 256 + tid) * 8;   // over L*24*49152
    long ln = j8 / 49152, rem = j8 % 49152;
    const float* src = &tmp_Win[ln * 49152 + rem];
    float4 v0 = *(const float4*)src, v1 = *(const float4*)(src + 4);
    union { bf16 h[8]; uint4 v; } pk;
    pk.h[0] = __float2bfloat16(v0.x); pk.h[1] = __float2bfloat16(v0.y);
    pk.h[2] = __float2bfloat16(v0.z); pk.h[3] = __float2bfloat16(v0.w);
    pk.h[4] = __float2bfloat16(v1.x); pk.h[5] = __float2bfloat16(v1.y);
    pk.h[6] = __float2bfloat16(v1.z); pk.h[7] = __float2bfloat16(v1.w);
    *(uint4*)&spW[ln * 98304 + 49152 + rem] = pk.v;
  } else if (bid < OFF_SPB) {
    // ---- cvt toWb ----
    int i8 = ((bid - OFF_CVT) * 256 + tid) * 8;
    float4 v0 = *(const float4*)(tmp_Wout + i8);
    float4 v1 = *(const float4*)(tmp_Wout + i8 + 4);
    union { bf16 h[8]; uint4 v; } pk;
    pk.h[0] = __float2bfloat16(v0.x); pk.h[1] = __float2bfloat16(v0.y);
    pk.h[2] = __float2bfloat16(v0.z); pk.h[3] = __float2bfloat16(v0.w);
    pk.h[4] = __float2bfloat16(v1.x); pk.h[5] = __float2bfloat16(v1.y);
    pk.h[6] = __float2bfloat16(v1.z); pk.h[7] = __float2bfloat16(v1.w);
    *(uint4*)(toWb + i8) = pk.v;
  } else if (bid < OFF_W1) {
    // ---- build_spb ----
    int i = (bid - OFF_SPB) * 256 + tid;
    int r = i % 768;
    int n = (i / 768) % 24;
    int l = i / (768 * 24);
    int hh = (r & 127) >> 4, f = r & 15;
    float v;
    if (r < 128)      v = sp_bq[(((size_t)l * kH + hh) * kN + n) * kF + f];
    else if (r < 256) v = sp_bk[((size_t)l * kH + hh) * kF + f];
    else if (r < 384) v = sp_bv[((size_t)l * kH + hh) * kF + f];
    else              v = tmp_bin[((size_t)l * kN + n) * 384 + (r - 384)];
    spbc[i] = v;
  } else if (bid < OFF_W2) {
    // ---- trans_cvt W1: fp32 (kND x kFF) -> bf16 (kFF x kND), per l ----
    int id2 = bid - OFF_W1;
    int bz = id2 / (16 * 48);
    int rem = id2 % (16 * 48);
    trans_cvt_body(ff_W1 + (size_t)bz * kND * kFF, W1t + (size_t)bz * kFF * kND,
                   kND, kFF, rem % 16, rem / 16, (float(*)[65])sm, tid);
  } else if (bid < OFF_FIN) {
    // ---- trans_cvt W2: fp32 (kFF x kND) -> bf16 (kND x kFF), per l ----
    int id2 = bid - OFF_W2;
    int bz = id2 / (48 * 16);
    int rem = id2 % (48 * 16);
    trans_cvt_body(ff_W2 + (size_t)bz * kFF * kND, W2t + (size_t)bz * kND * kFF,
                   kFF, kND, rem % 48, rem / 48, (float(*)[65])sm, tid);
  } else {
    // ---- trans_cvt fin_W: fp32 (kND x kNM) -> bf16 (kNM x kND) ----
    int id2 = bid - OFF_FIN;
    trans_cvt_body(fin_W, finWt, kND, kNM, id2 % 4, id2 / 4, (float(*)[65])sm, tid);
  }
}

// ---------------------------------------------------------------------------
// Fused attention, 256 threads/block. Blocks [0,kP): spatial (loader uses all
// 256 threads, compute guarded tid<192). Blocks [kP,kP+1536): temporal MFMA,
// restructured to 4 WAVES with acc[2][8] (64 VGPR for S vs r5's 128) so the
// fused kernel stays under the 128-VGPR occupancy cliff — this was r5's
// failure mode (148 VGPR -> 2 blocks/CU). Per-row arithmetic is bit-identical
// to the 2-wave version; rows are just redistributed across waves.
// LDS: max(37.2, 39.2) KB -> 4 blocks/CU.
// ---------------------------------------------------------------------------
__global__ __launch_bounds__(256) void attn_kernel(
    const bf16* __restrict__ qkv, float* __restrict__ sp_out,
    bf16* __restrict__ ot)
{
  __shared__ __align__(16) char smem[39168];
  int tid = threadIdx.x;

  if (blockIdx.x < kP) {
    // ================= spatial attention =================
    int p = blockIdx.x;
    float* s = (float*)smem;                 // 24*388 floats = 37248 B
    for (int i = tid; i < 2304; i += 256) {
      int n = i / 96, c4 = (i % 96) * 4;
      ushort4 u = *(const ushort4*)((const ushort*)qkv + ((size_t)n * kP + p) * 768 + c4);
      float4 f;
      f.x = __bfloat162float(*(const bf16*)&u.x);
      f.y = __bfloat162float(*(const bf16*)&u.y);
      f.z = __bfloat162float(*(const bf16*)&u.z);
      f.w = __bfloat162float(*(const bf16*)&u.w);
      *(float4*)&s[n * 388 + c4] = f;
    }
    __syncthreads();
    if (tid < 192) {
      int hh = tid / 24, n = tid % 24;
      const float4* qr = (const float4*)(s + n * 388 + hh * 16);
      float4 q0 = qr[0], q1 = qr[1], q2 = qr[2], q3 = qr[3];
      float sc[24];
      float mx = -1e30f;
#pragma unroll
      for (int m = 0; m < 24; m++) {
        const float4* kr = (const float4*)(s + m * 388 + 128 + hh * 16);
        float4 k0 = kr[0], k1 = kr[1], k2 = kr[2], k3 = kr[3];
        float d = q0.x * k0.x + q0.y * k0.y + q0.z * k0.z + q0.w * k0.w
                + q1.x * k1.x + q1.y * k1.y + q1.z * k1.z + q1.w * k1.w
                + q2.x * k2.x + q2.y * k2.y + q2.z * k2.z + q2.w * k2.w
                + q3.x * k3.x + q3.y * k3.y + q3.z * k3.z + q3.w * k3.w;
        d *= 0.25f;
        sc[m] = d;
        mx = fmaxf(mx, d);
      }
      float sum = 0.f;
#pragma unroll
      for (int m = 0; m < 24; m++) { float e = __expf(sc[m] - mx); sc[m] = e; sum += e; }
      float inv = 1.f / sum;
      float4 o0 = {0,0,0,0}, o1 = {0,0,0,0}, o2 = {0,0,0,0}, o3 = {0,0,0,0};
#pragma unroll
      for (int m = 0; m < 24; m++) {
        const float4* vr = (const float4*)(s + m * 388 + 256 + hh * 16);
        float4 v0 = vr[0], v1 = vr[1], v2 = vr[2], v3 = vr[3];
        float w = sc[m];
        o0.x += w * v0.x; o0.y += w * v0.y; o0.z += w * v0.z; o0.w += w * v0.w;
        o1.x += w * v1.x; o1.y += w * v1.y; o1.z += w * v1.z; o1.w += w * v1.w;
        o2.x += w * v2.x; o2.y += w * v2.y; o2.z += w * v2.z; o2.w += w * v2.w;
        o3.x += w * v3.x; o3.y += w * v3.y; o3.z += w * v3.z; o3.w += w * v3.w;
      }
      float* orow = sp_out + (size_t)p * kND + n * kD + hh * 16;
      o0.x *= inv; o0.y *= inv; o0.z *= inv; o0.w *= inv;
      o1.x *= inv; o1.y *= inv; o1.z *= inv; o1.w *= inv;
      o2.x *= inv; o2.y *= inv; o2.z *= inv; o2.w *= inv;
      o3.x *= inv; o3.y *= inv; o3.z *= inv; o3.w *= inv;
      *(float4*)(orow)      = o0;
      *(float4*)(orow + 4)  = o1;
      *(float4*)(orow + 8)  = o2;
      *(float4*)(orow + 12) = o3;
    }
  } else {
    // ================= temporal attention (MFMA, 4 waves) =================
    int g = blockIdx.x - kP;
    int hh = g & 7, n = (g >> 3) % 24, b = g / 192;
    ushort (*Qs)[40]  = (ushort(*)[40])(smem);            // [0,10240)
    ushort (*Ks)[40]  = (ushort(*)[40])(smem + 10240);    // [10240,20480)
    ushort (*Ps)[136] = (ushort(*)[136])(smem);           // [0,34816) aliases Qs/Ks
    ushort (*Vt)[136] = (ushort(*)[136])(smem + 34816);   // [34816,39168)

    {
      int t = tid >> 1, e8 = (tid & 1) * 8;
      const ushort* src = (const ushort*)qkv +
          ((size_t)n * kP + (size_t)t * kB + b) * 768 + 384 + hh * 16 + e8;
      uint4 q = *(const uint4*)(src);
      uint4 k = *(const uint4*)(src + 128);
      uint4 v = *(const uint4*)(src + 256);
      *(uint4*)&Qs[t][e8] = q;
      *(uint4*)&Ks[t][e8] = k;
      *(uint4*)&Qs[t][16 + e8] = make_uint4(0, 0, 0, 0);
      *(uint4*)&Ks[t][16 + e8] = make_uint4(0, 0, 0, 0);
      const ushort* vp = (const ushort*)&v;
#pragma unroll
      for (int j = 0; j < 8; j++) Vt[e8 + j][t] = vp[j];
    }
    __syncthreads();

    int lane = tid & 63, w = tid >> 6;     // w in 0..3, each wave owns 32 rows
    int c = lane & 15, quad = lane >> 4;

    // S = Q K^T (rows w*32 + mt*16, mt in {0,1})
    bf16x8 aq[2];
#pragma unroll
    for (int mt = 0; mt < 2; mt++)
      aq[mt] = *(const bf16x8*)&Qs[w * 32 + mt * 16 + c][quad * 8];
    f32x4 acc[2][8];
#pragma unroll
    for (int nt = 0; nt < 8; nt++) {
      bf16x8 bk = *(const bf16x8*)&Ks[nt * 16 + c][quad * 8];
#pragma unroll
      for (int mt = 0; mt < 2; mt++) {
        f32x4 z = {0.f, 0.f, 0.f, 0.f};
        acc[mt][nt] = __builtin_amdgcn_mfma_f32_16x16x32_bf16(aq[mt], bk, z, 0, 0, 0);
      }
    }
    __syncthreads();   // Qs/Ks dead -> Ps may overwrite

    // softmax per row; rows t = w*32 + mt*16 + quad*4 + r, cols s = nt*16 + c
    f32x4 invv[2];
#pragma unroll
    for (int mt = 0; mt < 2; mt++) {
      int tbase = w * 32 + mt * 16 + quad * 4;
      f32x4 rm = {-1e30f, -1e30f, -1e30f, -1e30f};
#pragma unroll
      for (int nt = 0; nt < 8; nt++) {
        int s = nt * 16 + c;
#pragma unroll
        for (int r = 0; r < 4; r++) {
          float x = acc[mt][nt][r] * 0.25f + ((s < tbase + r) ? 1.f : 0.f);
          acc[mt][nt][r] = x;
          rm[r] = fmaxf(rm[r], x);
        }
      }
#pragma unroll
      for (int off = 1; off < 16; off <<= 1)
#pragma unroll
        for (int r = 0; r < 4; r++) rm[r] = fmaxf(rm[r], __shfl_xor(rm[r], off, 64));
      f32x4 rs = {0.f, 0.f, 0.f, 0.f};
#pragma unroll
      for (int nt = 0; nt < 8; nt++)
#pragma unroll
        for (int r = 0; r < 4; r++) {
          float pp = __expf(acc[mt][nt][r] - rm[r]);
          acc[mt][nt][r] = pp;
          rs[r] += pp;
        }
#pragma unroll
      for (int off = 1; off < 16; off <<= 1)
#pragma unroll
        for (int r = 0; r < 4; r++) rs[r] += __shfl_xor(rs[r], off, 64);
#pragma unroll
      for (int r = 0; r < 4; r++) invv[mt][r] = 1.f / rs[r];
#pragma unroll
      for (int nt = 0; nt < 8; nt++)
#pragma unroll
        for (int r = 0; r < 4; r++) {
          bf16 pb = __float2bfloat16(acc[mt][nt][r]);
          Ps[tbase + r][nt * 16 + c] = *(ushort*)&pb;
        }
    }
    __syncthreads();   // all P rows written before PV reads across rows

    // O = P V
    f32x4 o[2] = {};
#pragma unroll
    for (int ks = 0; ks < 128; ks += 32) {
      bf16x8 bv = *(const bf16x8*)&Vt[c][ks + quad * 8];
#pragma unroll
      for (int mt = 0; mt < 2; mt++) {
        bf16x8 ap = *(const bf16x8*)&Ps[w * 32 + mt * 16 + c][ks + quad * 8];
        o[mt] = __builtin_amdgcn_mfma_f32_16x16x32_bf16(ap, bv, o[mt], 0, 0, 0);
      }
    }

#pragma unroll
    for (int mt = 0; mt < 2; mt++) {
#pragma unroll
      for (int r = 0; r < 4; r++) {
        int t = w * 32 + mt * 16 + quad * 4 + r;
        float val = o[mt][r] * invv[mt][r];
        ot[((size_t)n * kP + (size_t)t * kB + b) * 128 + hh * 16 + c] = __float2bfloat16(val);
      }
    }
  }
}

// ---------------------------------------------------------------------------
// Fused: a2 = LN(sp+h) + LN(tp+h); float4 traffic; writes a2 fp32 + bf16
// ---------------------------------------------------------------------------
__global__ __launch_bounds__(256) void fuse_a2_kernel(
    const float* __restrict__ sp, const float* __restrict__ tp,
    const float* __restrict__ h, const float* __restrict__ g,
    const float* __restrict__ be, float* __restrict__ a2, bf16* __restrict__ a2b)
{
  int row = blockIdx.x;
  const float4* s1p = (const float4*)(sp + (size_t)row * kND);
  const float4* s2p = (const float4*)(tp + (size_t)row * kND);
  const float4* hp  = (const float4*)(h  + (size_t)row * kND);
  float4 x1[3], x2[3];
  float sum1 = 0.f, sum2 = 0.f;
#pragma unroll
  for (int i = 0; i < 3; i++) {
    int c = threadIdx.x + 256 * i;
    float4 hv = hp[c], a = s1p[c], bb = s2p[c];
    a.x += hv.x; a.y += hv.y; a.z += hv.z; a.w += hv.w;
    bb.x += hv.x; bb.y += hv.y; bb.z += hv.z; bb.w += hv.w;
    x1[i] = a; x2[i] = bb;
    sum1 += a.x + a.y + a.z + a.w;
    sum2 += bb.x + bb.y + bb.z + bb.w;
  }
  __shared__ float red1[4], red2[4];
#pragma unroll
  for (int o = 32; o > 0; o >>= 1) { sum1 += __shfl_down(sum1, o, 64); sum2 += __shfl_down(sum2, o, 64); }
  int wid = threadIdx.x >> 6;
  if ((threadIdx.x & 63) == 0) { red1[wid] = sum1; red2[wid] = sum2; }
  __syncthreads();
  float mean1 = (red1[0] + red1[1] + red1[2] + red1[3]) * (1.f / kND);
  float mean2 = (red2[0] + red2[1] + red2[2] + red2[3]) * (1.f / kND);
  __syncthreads();
  float v1 = 0.f, v2 = 0.f;
#pragma unroll
  for (int i = 0; i < 3; i++) {
    float4 a = x1[i], bb = x2[i];
    v1 += (a.x - mean1) * (a.x - mean1) + (a.y - mean1) * (a.y - mean1)
        + (a.z - mean1) * (a.z - mean1) + (a.w - mean1) * (a.w - mean1);
    v2 += (bb.x - mean2) * (bb.x - mean2) + (bb.y - mean2) * (bb.y - mean2)
        + (bb.z - mean2) * (bb.z - mean2) + (bb.w - mean2) * (bb.w - mean2);
  }
#pragma unroll
  for (int o = 32; o > 0; o >>= 1) { v1 += __shfl_down(v1, o, 64); v2 += __shfl_down(v2, o, 64); }
  if ((threadIdx.x & 63) == 0) { red1[wid] = v1; red2[wid] = v2; }
  __syncthreads();
  float r1 = rsqrtf((red1[0] + red1[1] + red1[2] + red1[3]) * (1.f / kND) + 1e-5f);
  float r2 = rsqrtf((red2[0] + red2[1] + red2[2] + red2[3]) * (1.f / kND) + 1e-5f);
  const float4* g4 = (const float4*)g;
  const float4* b4 = (const float4*)be;
#pragma unroll
  for (int i = 0; i < 3; i++) {
    int c = threadIdx.x + 256 * i;
    float4 gc = g4[c], bc = b4[c];
    float4 a = x1[i], bb = x2[i], o;
    o.x = (a.x - mean1) * r1 * gc.x + bc.x + (bb.x - mean2) * r2 * gc.x + bc.x;
    o.y = (a.y - mean1) * r1 * gc.y + bc.y + (bb.y - mean2) * r2 * gc.y + bc.y;
    o.z = (a.z - mean1) * r1 * gc.z + bc.z + (bb.z - mean2) * r2 * gc.z + bc.z;
    o.w = (a.w - mean1) * r1 * gc.w + bc.w + (bb.w - mean2) * r2 * gc.w + bc.w;
    *(float4*)(a2 + (size_t)row * kND + c * 4) = o;
    union { bf16 h4[4]; uint2 v; } pk;
    pk.h4[0] = __float2bfloat16(o.x); pk.h4[1] = __float2bfloat16(o.y);
    pk.h4[2] = __float2bfloat16(o.z); pk.h4[3] = __float2bfloat16(o.w);
    *(uint2*)(a2b + (size_t)row * kND + c * 4) = pk.v;
  }
}

// out = LN(a + b); float4 traffic; writes fp32 + bf16
__global__ __launch_bounds__(256) void add_ln_dual_kernel(
    const float* __restrict__ a, const float* __restrict__ b,
    const float* __restrict__ g, const float* __restrict__ be,
    float* __restrict__ out, bf16* __restrict__ outb)
{
  int row = blockIdx.x;
  const float4* ar = (const float4*)(a + (size_t)row * kND);
  const float4* br = (const float4*)(b + (size_t)row * kND);
  float4 v[3];
  float s = 0.f;
#pragma unroll
  for (int i = 0; i < 3; i++) {
    int c = threadIdx.x + 256 * i;
    float4 x = ar[c], y = br[c];
    x.x += y.x; x.y += y.y; x.z += y.z; x.w += y.w;
    v[i] = x;
    s += x.x + x.y + x.z + x.w;
  }
  __shared__ float red[4];
#pragma unroll
  for (int o = 32; o > 0; o >>= 1) s += __shfl_down(s, o, 64);
  int wid = threadIdx.x >> 6;
  if ((threadIdx.x & 63) == 0) red[wid] = s;
  __syncthreads();
  float mean = (red[0] + red[1] + red[2] + red[3]) * (1.f / kND);
  __syncthreads();
  float vs = 0.f;
#pragma unroll
  for (int i = 0; i < 3; i++) {
    float4 x = v[i];
    vs += (x.x - mean) * (x.x - mean) + (x.y - mean) * (x.y - mean)
        + (x.z - mean) * (x.z - mean) + (x.w - mean) * (x.w - mean);
  }
#pragma unroll
  for (int o = 32; o > 0; o >>= 1) vs += __shfl_down(vs, o, 64);
  if ((threadIdx.x & 63) == 0) red[wid] = vs;
  __syncthreads();
  float rstd = rsqrtf((red[0] + red[1] + red[2] + red[3]) * (1.f / kND) + 1e-5f);
  const float4* g4 = (const float4*)g;
  const float4* b4 = (const float4*)be;
#pragma unroll
  for (int i = 0; i < 3; i++) {
    int c = threadIdx.x + 256 * i;
    float4 gc = g4[c], bc = b4[c], x = v[i], o;
    o.x = (x.x - mean) * rstd * gc.x + bc.x;
    o.y = (x.y - mean) * rstd * gc.y + bc.y;
    o.z = (x.z - mean) * rstd * gc.z + bc.z;
    o.w = (x.w - mean) * rstd * gc.w + bc.w;
    *(float4*)(out + (size_t)row * kND + c * 4) = o;
    union { bf16 h4[4]; uint2 v2; } pk;
    pk.h4[0] = __float2bfloat16(o.x); pk.h4[1] = __float2bfloat16(o.y);
    pk.h4[2] = __float2bfloat16(o.z); pk.h4[3] = __float2bfloat16(o.w);
    *(uint2*)(outb + (size_t)row * kND + c * 4) = pk.v2;
  }
}

// FF1 split-K reduce: f1b[i] = bf16(p0+p1+p2 + bias[col])
__global__ __launch_bounds__(256) void ff1_reduce_kernel(
    const float* __restrict__ part, const float* __restrict__ bias,
    bf16* __restrict__ out)
{
  int i4 = (blockIdx.x * 256 + threadIdx.x) * 4;   // grid covers kP*kFF/4
  const size_t S = (size_t)kP * kFF;
  float4 p0 = *(const float4*)(part + i4);
  float4 p1 = *(const float4*)(part + S + i4);
  float4 p2 = *(const float4*)(part + 2 * S + i4);
  int col = i4 & (kFF - 1);
  float4 bb = *(const float4*)(bias + col);
  union { bf16 h4[4]; uint2 v; } pk;
  pk.h4[0] = __float2bfloat16(p0.x + p1.x + p2.x + bb.x);
  pk.h4[1] = __float2bfloat16(p0.y + p1.y + p2.y + bb.y);
  pk.h4[2] = __float2bfloat16(p0.z + p1.z + p2.z + bb.z);
  pk.h4[3] = __float2bfloat16(p0.w + p1.w + p2.w + bb.w);
  *(uint2*)(out + i4) = pk.v;
}

// Final: out[b,t,c] = sum_z part[z][(t*B+b)*216+c] + fin_b[c] + inputs[b,t,c]
__global__ __launch_bounds__(256) void final_reduce_add_kernel(
    const float* __restrict__ part, const float* __restrict__ fin_b,
    const float* __restrict__ inp, float* __restrict__ out)
{
  int i = blockIdx.x * 256 + threadIdx.x;
  if (i >= kB * kT * kNM) return;
  int c = i % kNM;
  int rem = i / kNM;
  int t = rem % kT, b = rem / kT;
  size_t pi = (size_t)(t * kB + b) * kNM + c;
  const size_t S = (size_t)kP * kNM;
  float v = fin_b[c] + inp[i];
#pragma unroll
  for (int z = 0; z < 8; z++) v += part[z * S + pi];
  out[i] = v;
}

// ---------------------------------------------------------------------------
extern "C" void kernel_launch(void* const* d_in, const int* in_sizes, int n_in,
                              void* d_out, int out_size, void* d_ws, size_t ws_size,
                              hipStream_t stream)
{
  const float* inputs   = (const float*)d_in[0];
  const float* emb_W    = (const float*)d_in[1];
  const float* emb_b    = (const float*)d_in[2];
  const float* sp_Wq    = (const float*)d_in[3];
  const float* sp_bq    = (const float*)d_in[4];
  const float* sp_Wk    = (const float*)d_in[5];
  const float* sp_bk    = (const float*)d_in[6];
  const float* sp_Wv    = (const float*)d_in[7];
  const float* sp_bv    = (const float*)d_in[8];
  const float* tmp_Win  = (const float*)d_in[9];
  const float* tmp_bin  = (const float*)d_in[10];
  const float* tmp_Wout = (const float*)d_in[11];
  const float* tmp_bout = (const float*)d_in[12];
  const float* ff_W1    = (const float*)d_in[13];
  const float* ff_b1    = (const float*)d_in[14];
  const float* ff_W2    = (const float*)d_in[15];
  const float* ff_b2    = (const float*)d_in[16];
  const float* ln_g     = (const float*)d_in[17];
  const float* ln_b     = (const float*)d_in[18];
  const float* fin_W    = (const float*)d_in[19];
  const float* fin_b    = (const float*)d_in[20];
  float* out = (float*)d_out;

  // ---- workspace layout ----
  char* wp = (char*)d_ws;
  size_t off = 0;
  auto alloc = [&](size_t bytes) { void* p = wp + off; off += (bytes + 255) & ~(size_t)255; return p; };
  bf16* spW   = (bf16*)alloc((size_t)kL * 24 * 768 * 128 * 2);  // fused qkv weights
  bf16* toWb  = (bf16*)alloc((size_t)kL * 24 * 128 * 128 * 2);
  bf16* W1t   = (bf16*)alloc((size_t)kL * kFF * kND * 2);
  bf16* W2t   = (bf16*)alloc((size_t)kL * kND * kFF * 2);
  bf16* finWt = (bf16*)alloc((size_t)kNM * kND * 2);
  float* spbc = (float*)alloc((size_t)kL * 24 * 768 * 4);
  float* hb   = (float*)alloc((size_t)kP * kND * 4);
  bf16*  hbb  = (bf16*) alloc((size_t)kP * kND * 2);
  bf16*  qkvb = (bf16*) alloc((size_t)24 * kP * 768 * 2);   // fused spatial+temporal qkv
  float* sp   = (float*)alloc((size_t)kP * kND * 4);        // spatial out; FF1 partials
  float* tp   = (float*)alloc((size_t)kP * kND * 4);        // temporal out; FF2 out; final partials
  float* a2   = (float*)alloc((size_t)kP * kND * 4);
  bf16*  a2b  = (bf16*) alloc((size_t)kP * kND * 2);
  bf16*  f1b  = (bf16*) alloc((size_t)kP * kFF * 2);
  bf16*  otb  = (bf16*) alloc((size_t)24 * kP * 128 * 2);
  float* ffpart  = sp;   // 3 * kP*kFF fp32 = 12 MB (sp dead during FF)
  float* finpart = tp;   // 8 * kP*kNM fp32 = 6.9 MB (tp dead after loop)

  // ---- all weight prep + embedding: ONE dispatch ----
  prep_kernel<<<NB_PREP, 256, 0, stream>>>(
      sp_Wq, sp_Wk, sp_Wv, tmp_Win, spW,
      tmp_Wout, toWb,
      sp_bq, sp_bk, sp_bv, tmp_bin, spbc,
      ff_W1, W1t, ff_W2, W2t, fin_W, finWt,
      inputs, emb_W, emb_b, hb, hbb);

  for (int l = 0; l < kL; l++) {
    const float* lg = ln_g + (size_t)l * kND;
    const float* lb = ln_b + (size_t)l * kND;

    // fused spatial+temporal qkv: groups n; C = qkvb (n, p, 768) bf16
    mfma_gemm<128, 128, true><<<dim3(6, 8, 24), 256, 0, stream>>>(
        hbb, spW + (size_t)l * 24 * 768 * 128, spbc + (size_t)l * 24 * 768, qkvb,
        kP, 768, 128, /*ldB*/128, /*sAi*/kND, /*sCi*/768,
        /*offAg*/128, /*offBg*/768 * 128, /*offCg*/(long)kP * 768, /*sBg*/768);

    // spatial + temporal attention, ONE dispatch (VGPR-balanced this time)
    attn_kernel<<<kP + kB * 24 * 8, 256, 0, stream>>>(qkvb, sp, otb);

    // temporal out-proj: 64x64 tiles -> 768 blocks
    mfma_gemm<64, 64, false><<<dim3(2, 16, 24), 256, 0, stream>>>(
        otb, toWb + (size_t)l * 24 * 128 * 128, tmp_bout + (size_t)l * 24 * 128, tp,
        kP, 128, 128, /*ldB*/128, /*sAi*/128, /*sCi*/kND,
        /*offAg*/(long)kP * 128, /*offBg*/128 * 128, /*offCg*/128, /*sBg*/128);

    fuse_a2_kernel<<<kP, 256, 0, stream>>>(sp, tp, hb, lg, lb, a2, a2b);

    // FF1 split-K=3: 768 blocks, K-chunk 1024, fp32 partials -> ffpart
    mfma_gemm<64, 64, false><<<dim3(kFF / 64, kP / 64, 3), 256, 0, stream>>>(
        a2b, W1t + (size_t)l * kFF * kND, nullptr, ffpart,
        kP, kFF, /*K*/kND / 3, /*ldB*/kND, /*sAi*/kND, /*sCi*/kFF,
        /*offAg*/kND / 3, /*offBg*/kND / 3, /*offCg*/(long)kP * kFF, /*sBg*/0);
    ff1_reduce_kernel<<<(kP * kFF / 4) / 256, 256, 0, stream>>>(
        ffpart, ff_b1 + (size_t)l * kFF, f1b);

    // FF2: 64x64 tiles -> 768 blocks
    mfma_gemm<64, 64, false><<<dim3(kND / 64, kP / 64, 1), 256, 0, stream>>>(
        f1b, W2t + (size_t)l * kND * kFF, ff_b2 + (size_t)l * kND, tp,
        kP, kND, kFF, /*ldB*/kFF, /*sAi*/kFF, /*sCi*/kND, 0, 0, 0, 0);

    add_ln_dual_kernel<<<kP, 256, 0, stream>>>(tp, a2, lg, lb, hb, hbb);
  }

  // final projection: split-K=8 (K-chunk 384) -> 512 blocks; fused reduce+residual
  mfma_gemm<64, 64, false><<<dim3((kNM + 63) / 64, kP / 64, 8), 256, 0, stream>>>(
      hbb, finWt, nullptr, finpart,
      kP, kNM, /*K*/kND / 8, /*ldB*/kND, /*sAi*/kND, /*sCi*/kNM,
      /*offAg*/kND / 8, /*offBg*/kND / 8, /*offCg*/(long)kP * kNM, /*sBg*/0);
  final_reduce_add_kernel<<<(kB * kT * kNM + 255) / 256, 256, 0, stream>>>(
      finpart, fin_b, inputs, out);
}